// Round 9
// baseline (41.848 us; speedup 1.0000x reference)
//
#include <hip/hip_runtime.h>

// bf16-MFMA aspect-grouped 2-layer MLP. 3 graph nodes:
//   memset(out)
//   prep:  W1 [20][768k][256c] fp32 -> W1T [20][256c][768k] bf16 (LDS-tiled
//          transpose, RTN), and X fp32 -> Xbf bf16. Both into ws.
//   gemm:  grid (84 chunks, 4 hs) x 256 thr. Ballot-bucket 1024 aspect_ids ->
//          chunk's 16 sample ids; per K-chunk of 192: stage X[16][192] and
//          W1T[64][192] bf16 slices in LDS (linear b128), each wave does
//          6 x mfma_f32_16x16x32_bf16 (A=X samples, B=W1T cols, both
//          k-contiguous); epilogue: b1+ReLU+W2(+b2) and atomicAdd float2
//          logits into zeroed out. fp32 accumulate throughout.

constexpr int D  = 768;
constexpr int H  = 256;
constexpr int NA = 20;
constexpr int NB = 1024;
constexpr int S  = 16;             // samples per chunk
constexpr int CH_CAP = 84;         // >= total chunks (<=82)
constexpr int HSN = 4;             // 64-col slices
constexpr int KC  = 192;           // K chunk
constexpr int NSTEP = D / KC;      // 4
constexpr int XRW = KC + 8;        // 200 shorts (400B rows: 2-way banks, free)
constexpr int WRW = KC + 8;        // 200

constexpr size_t W1T_SHORTS = (size_t)NA * H * D;   // 3,932,160
constexpr size_t XBF_SHORTS = (size_t)NB * D;       // 786,432
constexpr size_t WS_NEEDED  = (W1T_SHORTS + XBF_SHORTS) * 2;

typedef __attribute__((ext_vector_type(8))) short short8v;  // 8 bf16
typedef __attribute__((ext_vector_type(4))) float f32x4;

__device__ __forceinline__ unsigned short f2bf(float x) {   // RTN-even
    const unsigned u = __float_as_uint(x);
    return (unsigned short)((u + 0x7FFFu + ((u >> 16) & 1u)) >> 16);
}

__global__ __launch_bounds__(256) void prep_kernel(
    const float* __restrict__ W1, const float* __restrict__ X,
    unsigned short* __restrict__ W1T, unsigned short* __restrict__ Xbf)
{
    const int t = threadIdx.x;
    const int a = blockIdx.x;

    if (a == NA) {                       // X fp32 -> bf16 (48 blocks)
        const int cid = blockIdx.y * 4 + blockIdx.z;
        const float4* Xs = reinterpret_cast<const float4*>(X) + (size_t)cid * 4096;
        uint2* Xo = reinterpret_cast<uint2*>(Xbf) + (size_t)cid * 4096;
        #pragma unroll
        for (int p = 0; p < 16; ++p) {
            const int i = t + p * 256;
            const float4 v = Xs[i];
            uint2 o;
            o.x = (unsigned)f2bf(v.x) | ((unsigned)f2bf(v.y) << 16);
            o.y = (unsigned)f2bf(v.z) | ((unsigned)f2bf(v.w) << 16);
            Xo[i] = o;
        }
        return;
    }

    // W1 transpose: 64x64 tile (k0.., c0..) via LDS
    __shared__ float tile[64 * 68];      // stride 68: 16B-aligned rows
    const int k0 = blockIdx.y * 64, c0 = blockIdx.z * 64;
    const float4* src = reinterpret_cast<const float4*>(W1)
        + (size_t)a * 49152 + (size_t)k0 * 64 + (c0 >> 2);
    #pragma unroll
    for (int p = 0; p < 4; ++p) {
        const int i = t + p * 256;
        const int r = i >> 4, cq = i & 15;
        *reinterpret_cast<float4*>(&tile[r * 68 + cq * 4]) = src[(size_t)r * 64 + cq];
    }
    __syncthreads();
    #pragma unroll
    for (int p = 0; p < 2; ++p) {
        const int j = t + p * 256;
        const int cc = j >> 3, q = j & 7;     // out row c0+cc, k-slot q (8 k)
        unsigned o[4];
        #pragma unroll
        for (int m = 0; m < 4; ++m) {
            const unsigned short lo = f2bf(tile[(q * 8 + 2 * m) * 68 + cc]);
            const unsigned short hi = f2bf(tile[(q * 8 + 2 * m + 1) * 68 + cc]);
            o[m] = (unsigned)lo | ((unsigned)hi << 16);
        }
        *reinterpret_cast<uint4*>(
            &W1T[((size_t)(a * 256 + c0 + cc)) * D + k0 + q * 8]) =
            make_uint4(o[0], o[1], o[2], o[3]);
    }
}

__global__ __launch_bounds__(256, 4) void mfma_kernel(
    const unsigned short* __restrict__ Xbf,
    const int*            __restrict__ aids,
    const unsigned short* __restrict__ W1T,
    const float*          __restrict__ b1,
    const float*          __restrict__ W2,
    const float*          __restrict__ b2,
    float*                __restrict__ out)   // zeroed each launch
{
    __shared__ short smem[S * XRW + 64 * WRW];   // X 3200 sh, W1 12800 sh
    __shared__ int hist4[4][NA];
    __shared__ int cntf[NA];
    __shared__ int sidx[S];

    short* Xl = smem;
    short* Wl = smem + S * XRW;
    int*   ai = reinterpret_cast<int*>(Wl);      // prologue overlay (4KB<25.6KB)

    const int t = threadIdx.x;
    const int w = t >> 6, l = t & 63;
    const int c = blockIdx.x, hs = blockIdx.y;

    ai[t]       = aids[t];
    ai[t + 256] = aids[t + 256];
    ai[t + 512] = aids[t + 512];
    ai[t + 768] = aids[t + 768];
    __syncthreads();

    // wave w histograms ids [w*256, w*256+256) via ballots (deterministic)
    {
        const int i0 = ai[w * 256 + l],       i1 = ai[w * 256 + 64 + l];
        const int i2 = ai[w * 256 + 128 + l], i3 = ai[w * 256 + 192 + l];
        #pragma unroll
        for (int a = 0; a < NA; ++a) {
            const unsigned long long m0 = __ballot(i0 == a), m1 = __ballot(i1 == a);
            const unsigned long long m2 = __ballot(i2 == a), m3 = __ballot(i3 == a);
            if (l == 0) hist4[w][a] =
                __popcll(m0) + __popcll(m1) + __popcll(m2) + __popcll(m3);
        }
    }
    __syncthreads();
    if (t < NA) cntf[t] = hist4[0][t] + hist4[1][t] + hist4[2][t] + hist4[3][t];
    __syncthreads();

    // map chunk c -> (aid, jj, cv)
    int aid = -1, jj = 0, cv = 0;
    {
        int cb = 0;
        #pragma unroll
        for (int a = 0; a < NA; ++a) {
            const int n = cntf[a];
            const int ca = (n + S - 1) / S;
            if (aid < 0 && c < cb + ca) { aid = a; jj = c - cb; cv = min(S, n - jj * S); }
            cb += ca;
        }
    }
    if (aid < 0) return;

    // wave 0: stable extraction of occurrences jj*16 .. jj*16+cv-1
    if (w == 0) {
        const int j0 = jj * S;
        int run = 0;
        for (int base = 0; base < NB; base += 64) {
            const int id = ai[base + l];
            const unsigned long long m = __ballot(id == aid);
            const int pre = run + __popcll(m & ((1ull << l) - 1));
            if (id == aid) { const int r = pre - j0; if (r >= 0 && r < S) sidx[r] = base + l; }
            run += __popcll(m);
        }
    }
    __syncthreads();

    const size_t wrowbase = (size_t)(aid * H + hs * 64) * D;
    const int cg = l & 15, g = l >> 4;
    f32x4 acc = {0.f, 0.f, 0.f, 0.f};

    for (int st = 0; st < NSTEP; ++st) {
        const int k0 = st * KC;
        // stage X slice [16][192] bf16
        for (int i = t; i < S * (KC / 8); i += 256) {
            const int r = i / (KC / 8), q = i % (KC / 8);
            *reinterpret_cast<uint4*>(&Xl[r * XRW + q * 8]) =
                *reinterpret_cast<const uint4*>(
                    &Xbf[(size_t)sidx[min(r, cv - 1)] * D + k0 + q * 8]);
        }
        // stage W1T slice [64][192] bf16
        for (int i = t; i < 64 * (KC / 8); i += 256) {
            const int r = i / (KC / 8), q = i % (KC / 8);
            *reinterpret_cast<uint4*>(&Wl[r * WRW + q * 8]) =
                *reinterpret_cast<const uint4*>(
                    &W1T[wrowbase + (size_t)r * D + k0 + q * 8]);
        }
        __syncthreads();

        // A: row=sample=l&15, k=8*(l>>4)+j (k-contig). B: col=l&15, same k map.
        const short* xa = &Xl[cg * XRW + 8 * g];
        const short* wa = &Wl[(w * 16 + cg) * WRW + 8 * g];
        #pragma unroll
        for (int kk = 0; kk < KC; kk += 32) {
            const short8v av = *reinterpret_cast<const short8v*>(xa + kk);
            const short8v bv = *reinterpret_cast<const short8v*>(wa + kk);
            acc = __builtin_amdgcn_mfma_f32_16x16x32_bf16(av, bv, acc, 0, 0, 0);
        }
        __syncthreads();
    }

    // epilogue: D[row=4g+r][col=cg] (m89-verified layout)
    const int gcol = hs * 64 + w * 16 + cg;
    const float  b1v = b1[aid * H + gcol];
    const float2 w2v = *reinterpret_cast<const float2*>(&W2[(size_t)(aid * H + gcol) * 2]);
    float p0[4], p1[4];
    #pragma unroll
    for (int r = 0; r < 4; ++r) {
        const float o = fmaxf(acc[r] + b1v, 0.f);
        p0[r] = o * w2v.x;
        p1[r] = o * w2v.y;
    }
    #pragma unroll
    for (int m = 1; m < 16; m <<= 1) {
        #pragma unroll
        for (int r = 0; r < 4; ++r) {
            p0[r] += __shfl_xor(p0[r], m, 64);
            p1[r] += __shfl_xor(p1[r], m, 64);
        }
    }
    if (cg == 0) {
        const float2 b2v = *reinterpret_cast<const float2*>(&b2[aid * 2]);
        #pragma unroll
        for (int r = 0; r < 4; ++r) {
            const int s = g * 4 + r;
            if (s < cv) {                      // guard padded slots (atomics!)
                float q0 = p0[r], q1 = p1[r];
                if (hs == 0 && w == 0) { q0 += b2v.x; q1 += b2v.y; }
                atomicAdd(&out[sidx[s] * 2 + 0], q0);
                atomicAdd(&out[sidx[s] * 2 + 1], q1);
            }
        }
    }
}

// ---------------- fallback (round-1 monolithic kernel) ----------------
__global__ __launch_bounds__(256, 4) void aspect_mlp_fallback(
    const float* __restrict__ X, const int* __restrict__ aspect_ids,
    const float* __restrict__ W1_embs, const float* __restrict__ b1_embs,
    const float* __restrict__ W2_embs, const float* __restrict__ b2_embs,
    float* __restrict__ out)
{
    __shared__ float xs[D];
    __shared__ float pl[4][H];
    __shared__ float red[4][2];
    const int b = blockIdx.x, t = threadIdx.x, w = t >> 6, l = t & 63;
    const int aid = aspect_ids[b];
    const float4* Xr = reinterpret_cast<const float4*>(X + (size_t)b * D);
    if (t < D / 4) reinterpret_cast<float4*>(xs)[t] = Xr[t];
    __syncthreads();
    const float4* W1v = reinterpret_cast<const float4*>(W1_embs + (size_t)aid * (D * H));
    float4 acc = make_float4(0.f, 0.f, 0.f, 0.f);
    const int d0 = w * (D / 4);
    for (int d = d0; d < d0 + D / 4; ++d) {
        const float xv = xs[d];
        const float4 wv = W1v[d * (H / 4) + l];
        acc.x = fmaf(xv, wv.x, acc.x); acc.y = fmaf(xv, wv.y, acc.y);
        acc.z = fmaf(xv, wv.z, acc.z); acc.w = fmaf(xv, wv.w, acc.w);
    }
    reinterpret_cast<float4*>(pl[w])[l] = acc;
    __syncthreads();
    const float o = fmaxf(pl[0][t] + pl[1][t] + pl[2][t] + pl[3][t] + b1_embs[aid * H + t], 0.f);
    const float2 w2 = reinterpret_cast<const float2*>(W2_embs)[aid * H + t];
    float p0 = o * w2.x, p1 = o * w2.y;
    for (int s = 32; s; s >>= 1) { p0 += __shfl_xor(p0, s, 64); p1 += __shfl_xor(p1, s, 64); }
    if (l == 0) { red[w][0] = p0; red[w][1] = p1; }
    __syncthreads();
    if (t == 0) {
        const float2 bias2 = reinterpret_cast<const float2*>(b2_embs)[aid];
        out[b * 2 + 0] = red[0][0] + red[1][0] + red[2][0] + red[3][0] + bias2.x;
        out[b * 2 + 1] = red[0][1] + red[1][1] + red[2][1] + red[3][1] + bias2.y;
    }
}

extern "C" void kernel_launch(void* const* d_in, const int* in_sizes, int n_in,
                              void* d_out, int out_size, void* d_ws, size_t ws_size,
                              hipStream_t stream) {
    const float* X          = (const float*)d_in[0];
    const int*   aspect_ids = (const int*)d_in[1];
    const float* W1_embs    = (const float*)d_in[2];
    const float* b1_embs    = (const float*)d_in[3];
    const float* W2_embs    = (const float*)d_in[4];
    const float* b2_embs    = (const float*)d_in[5];
    float*       out        = (float*)d_out;

    const int Brt = in_sizes[0] / D;
    const int na  = in_sizes[2] / (D * H);

    if (Brt != NB || na != NA || ws_size < WS_NEEDED) {
        aspect_mlp_fallback<<<Brt, 256, 0, stream>>>(
            X, aspect_ids, W1_embs, b1_embs, W2_embs, b2_embs, out);
        return;
    }

    unsigned short* W1T = (unsigned short*)d_ws;
    unsigned short* Xbf = W1T + W1T_SHORTS;

    hipMemsetAsync(d_out, 0, (size_t)out_size * sizeof(float), stream);
    prep_kernel<<<dim3(NA + 1, 12, 4), 256, 0, stream>>>(W1_embs, X, W1T, Xbf);
    mfma_kernel<<<dim3(CH_CAP, HSN), 256, 0, stream>>>(
        Xbf, aspect_ids, W1T, b1_embs, W2_embs, b2_embs, out);
}

// Round 10
// 27.187 us; speedup vs baseline: 1.5393x; 1.5393x over previous
//
#include <hip/hip_runtime.h>

// Aspect-owned tiled 2-layer MLP, 2 dispatches, no atomics/fences.
//   gemm1:  grid (20 aspects, 4 col-slices, 8 d-slices) x 256 thr.
//           W1 tile (96x64 fp32, 25KB) prefetched into registers FIRST (hides
//           cold-HBM latency under prologue), committed to LDS after the
//           wave-0 ballot scan; per 16-sample chunk: stage X slice, 4-sample
//           x 4-col register blocking from LDS x LDS (waves split K=96),
//           cross-wave LDS reduce, write disjoint bf16 partials
//           part[sample][dk][col] (b1 folded at dk==0).
//   finish: per sample: sum 8 bf16 dk-partials (fp32), ReLU, x W2 + b2 -> out.

constexpr int D  = 768;
constexpr int H  = 256;
constexpr int NA = 20;
constexpr int NB = 1024;
constexpr int S  = 16;            // samples per chunk
constexpr int DKN = 8;            // d-slices
constexpr int KS  = D / DKN;      // 96 rows per block
constexpr int HSN = 4;            // 64-col slices
constexpr int KT  = KS / 4;       // 24 k per wave
constexpr int QR  = KS / 4;       // 24 float4 per staged x row
constexpr int XROW  = KS + 4;     // 100 (pad)
constexpr int W1ROW = 68;         // 64 + 4 (pad)

// smem layout (float offsets)
constexpr int SM_XT   = KS * W1ROW;          // w1t: [96][68]      = 6528
constexpr int SM_RED  = SM_XT + S * XROW;    // xt:  [16][100]     @6528
constexpr int SM_SIDX = SM_RED + 4096;       // red: [4][16][16]f4 @8128 (16KB)
constexpr int SM_TOT  = SM_SIDX + NB + S;    // sidx:[1024+16]     @12224
constexpr size_t WS_NEEDED = (size_t)NB * DKN * H * 2;   // bf16 part: 4 MB

__device__ __forceinline__ float4 fma4(float x, float4 w, float4 a) {
    a.x = fmaf(x, w.x, a.x); a.y = fmaf(x, w.y, a.y);
    a.z = fmaf(x, w.z, a.z); a.w = fmaf(x, w.w, a.w);
    return a;
}
__device__ __forceinline__ unsigned f2bf(float x) {   // RTN-even, low 16
    const unsigned u = __float_as_uint(x);
    return (u + 0x7FFFu + ((u >> 16) & 1u)) >> 16;
}
__device__ __forceinline__ float bflo(unsigned u) { return __uint_as_float(u << 16); }
__device__ __forceinline__ float bfhi(unsigned u) { return __uint_as_float(u & 0xFFFF0000u); }

__global__ __launch_bounds__(256, 3) void gemm1_kernel(
    const float* __restrict__ X,
    const int*   __restrict__ aids,
    const float* __restrict__ W1,
    const float* __restrict__ b1,
    unsigned short* __restrict__ part)   // bf16 [NB][DKN][H]
{
    __shared__ __align__(16) float smem[SM_TOT];
    __shared__ int n_sh;

    float*  w1t  = smem;
    float*  xt   = smem + SM_XT;
    float4* red4 = reinterpret_cast<float4*>(smem + SM_RED);
    int*    sidx = reinterpret_cast<int*>(smem + SM_SIDX);
    int*    ai   = reinterpret_cast<int*>(smem + SM_RED);   // prologue overlay

    const int t = threadIdx.x;
    const int w = t >> 6, l = t & 63;
    const int aid = blockIdx.x;        // aspect
    const int hs  = blockIdx.y;        // 64-col slice
    const int dk  = blockIdx.z;        // 96-row d-slice

    // 1) issue W1 tile loads FIRST (in flight through the whole prologue)
    const float* W1s = W1 + (size_t)aid * D * H + (size_t)dk * KS * H + hs * 64;
    float4 wreg[6];
    #pragma unroll
    for (int i = 0; i < 6; ++i) {
        const int idx = t + i * 256;
        const int r = idx >> 4, cc = idx & 15;
        wreg[i] = *reinterpret_cast<const float4*>(&W1s[(size_t)r * H + cc * 4]);
    }

    // 2) stage aspect ids (overlaid on red region)
    ai[t]       = aids[t];
    ai[t + 256] = aids[t + 256];
    ai[t + 512] = aids[t + 512];
    ai[t + 768] = aids[t + 768];
    __syncthreads();

    // 3) wave 0: stable ballot-scan -> full sample list + pad to x16
    if (w == 0) {
        int run = 0;
        for (int base = 0; base < NB; base += 64) {
            const int id = ai[base + l];
            const unsigned long long m = __ballot(id == aid);
            const int pre = run + __popcll(m & ((1ull << l) - 1));
            if (id == aid) sidx[pre] = base + l;
            run += __popcll(m);
        }
        if (run > 0) {
            const int last = sidx[run - 1];          // own-wave write, ordered
            const int npad = ((run + S - 1) / S) * S;
            if (l < S && run + l < npad) sidx[run + l] = last;
        }
        if (l == 0) n_sh = run;
    }
    __syncthreads();
    const int n = n_sh;
    if (n == 0) return;                // uniform exit

    // 4) commit W1 tile to LDS (padded rows, as R7)
    #pragma unroll
    for (int i = 0; i < 6; ++i) {
        const int idx = t + i * 256;
        const int r = idx >> 4, cc = idx & 15;
        *reinterpret_cast<float4*>(&w1t[r * W1ROW + cc * 4]) = wreg[i];
    }
    // barrier comes from the X-stage sync below (covers w1t too)

    const int sq = l >> 4;            // sample quad 0..3
    const int cq = l & 15;            // col quad 0..15
    const float* wb = w1t + (w * KT) * W1ROW + cq * 4;

    for (int ch = 0; ch * S < n; ++ch) {
        const int cv = min(S, n - ch * S);

        // stage 16 X rows (this d-slice: 24 float4 each); padded sidx
        for (int i = t; i < S * QR; i += 256) {
            const int r = i / QR, q = i - r * QR;
            *reinterpret_cast<float4*>(&xt[r * XROW + q * 4]) =
                *reinterpret_cast<const float4*>(
                    &X[(size_t)sidx[ch * S + r] * D + dk * KS + q * 4]);
        }
        __syncthreads();

        // LDS x LDS compute: wave w covers k in [w*24, w*24+24)
        const float* xb = xt + (sq * 4) * XROW + w * KT;
        float4 a0 = {0,0,0,0}, a1 = {0,0,0,0}, a2 = {0,0,0,0}, a3 = {0,0,0,0};
        #pragma unroll
        for (int k4 = 0; k4 < KT; k4 += 4) {
            const float4 x0 = *reinterpret_cast<const float4*>(xb + k4);
            const float4 x1 = *reinterpret_cast<const float4*>(xb + XROW + k4);
            const float4 x2 = *reinterpret_cast<const float4*>(xb + 2 * XROW + k4);
            const float4 x3 = *reinterpret_cast<const float4*>(xb + 3 * XROW + k4);
            const float* wp = wb + k4 * W1ROW;
            float4 wv;
            wv = *reinterpret_cast<const float4*>(wp);
            a0 = fma4(x0.x, wv, a0); a1 = fma4(x1.x, wv, a1);
            a2 = fma4(x2.x, wv, a2); a3 = fma4(x3.x, wv, a3);
            wv = *reinterpret_cast<const float4*>(wp + W1ROW);
            a0 = fma4(x0.y, wv, a0); a1 = fma4(x1.y, wv, a1);
            a2 = fma4(x2.y, wv, a2); a3 = fma4(x3.y, wv, a3);
            wv = *reinterpret_cast<const float4*>(wp + 2 * W1ROW);
            a0 = fma4(x0.z, wv, a0); a1 = fma4(x1.z, wv, a1);
            a2 = fma4(x2.z, wv, a2); a3 = fma4(x3.z, wv, a3);
            wv = *reinterpret_cast<const float4*>(wp + 3 * W1ROW);
            a0 = fma4(x0.w, wv, a0); a1 = fma4(x1.w, wv, a1);
            a2 = fma4(x2.w, wv, a2); a3 = fma4(x3.w, wv, a3);
        }

        // cross-wave reduce
        red4[(w * 16 + sq * 4 + 0) * 16 + cq] = a0;
        red4[(w * 16 + sq * 4 + 1) * 16 + cq] = a1;
        red4[(w * 16 + sq * 4 + 2) * 16 + cq] = a2;
        red4[(w * 16 + sq * 4 + 3) * 16 + cq] = a3;
        __syncthreads();

        {
            const int s = t >> 4, q = t & 15;
            float4 v = red4[s * 16 + q];
            #pragma unroll
            for (int ww = 1; ww < 4; ++ww) {
                const float4 r = red4[ww * 256 + s * 16 + q];
                v.x += r.x; v.y += r.y; v.z += r.z; v.w += r.w;
            }
            if (s < cv) {
                if (dk == 0) {      // fold b1 exactly once
                    const float4 bv = *reinterpret_cast<const float4*>(
                        &b1[(size_t)aid * H + hs * 64 + q * 4]);
                    v.x += bv.x; v.y += bv.y; v.z += bv.z; v.w += bv.w;
                }
                uint2 o;
                o.x = f2bf(v.x) | (f2bf(v.y) << 16);
                o.y = f2bf(v.z) | (f2bf(v.w) << 16);
                const int sid = sidx[ch * S + s];
                *reinterpret_cast<uint2*>(
                    &part[((size_t)sid * DKN + dk) * H + hs * 64 + q * 4]) = o;
            }
        }
        // next X-stage touches xt only; the sync after it orders red4 reuse.
    }
}

__global__ __launch_bounds__(256) void finish_kernel(
    const int*            __restrict__ aids,
    const unsigned short* __restrict__ part,
    const float*          __restrict__ W2,
    const float*          __restrict__ b2,
    float*                __restrict__ out)
{
    const int w = threadIdx.x >> 6, l = threadIdx.x & 63;
    const int s = blockIdx.x * 4 + w;       // one sample per wave
    const int aid = aids[s];

    const unsigned short* ps = part + (size_t)s * DKN * H + l * 4;
    float4 v = {0, 0, 0, 0};
    #pragma unroll
    for (int dk = 0; dk < DKN; ++dk) {
        const uint2 r = *reinterpret_cast<const uint2*>(ps + dk * H);
        v.x += bflo(r.x); v.y += bfhi(r.x);
        v.z += bflo(r.y); v.w += bfhi(r.y);
    }
    float4 o;
    o.x = fmaxf(v.x, 0.f);
    o.y = fmaxf(v.y, 0.f);
    o.z = fmaxf(v.z, 0.f);
    o.w = fmaxf(v.w, 0.f);

    const float4* W2v = reinterpret_cast<const float4*>(&W2[(size_t)aid * H * 2 + l * 8]);
    const float4 w2a = W2v[0], w2b = W2v[1];
    float p0 = o.x * w2a.x + o.y * w2a.z + o.z * w2b.x + o.w * w2b.z;
    float p1 = o.x * w2a.y + o.y * w2a.w + o.z * w2b.y + o.w * w2b.w;
    #pragma unroll
    for (int m = 1; m < 64; m <<= 1) {
        p0 += __shfl_xor(p0, m, 64);
        p1 += __shfl_xor(p1, m, 64);
    }
    if (l == 0) {
        const float2 bias2 = reinterpret_cast<const float2*>(b2)[aid];
        reinterpret_cast<float2*>(out)[s] = make_float2(p0 + bias2.x, p1 + bias2.y);
    }
}

// ---------------- fallback (round-1 monolithic kernel) ----------------
__global__ __launch_bounds__(256, 4) void aspect_mlp_fallback(
    const float* __restrict__ X, const int* __restrict__ aspect_ids,
    const float* __restrict__ W1_embs, const float* __restrict__ b1_embs,
    const float* __restrict__ W2_embs, const float* __restrict__ b2_embs,
    float* __restrict__ out)
{
    __shared__ float xs[D];
    __shared__ float pl[4][H];
    __shared__ float red[4][2];
    const int b = blockIdx.x, t = threadIdx.x, w = t >> 6, l = t & 63;
    const int aid = aspect_ids[b];
    const float4* Xr = reinterpret_cast<const float4*>(X + (size_t)b * D);
    if (t < D / 4) reinterpret_cast<float4*>(xs)[t] = Xr[t];
    __syncthreads();
    const float4* W1v = reinterpret_cast<const float4*>(W1_embs + (size_t)aid * (D * H));
    float4 acc = make_float4(0.f, 0.f, 0.f, 0.f);
    const int d0 = w * (D / 4);
    for (int d = d0; d < d0 + D / 4; ++d) {
        const float xv = xs[d];
        const float4 wv = W1v[d * (H / 4) + l];
        acc.x = fmaf(xv, wv.x, acc.x); acc.y = fmaf(xv, wv.y, acc.y);
        acc.z = fmaf(xv, wv.z, acc.z); acc.w = fmaf(xv, wv.w, acc.w);
    }
    reinterpret_cast<float4*>(pl[w])[l] = acc;
    __syncthreads();
    const float o = fmaxf(pl[0][t] + pl[1][t] + pl[2][t] + pl[3][t] + b1_embs[aid * H + t], 0.f);
    const float2 w2 = reinterpret_cast<const float2*>(W2_embs)[aid * H + t];
    float p0 = o * w2.x, p1 = o * w2.y;
    for (int s = 32; s; s >>= 1) { p0 += __shfl_xor(p0, s, 64); p1 += __shfl_xor(p1, s, 64); }
    if (l == 0) { red[w][0] = p0; red[w][1] = p1; }
    __syncthreads();
    if (t == 0) {
        const float2 bias2 = reinterpret_cast<const float2*>(b2_embs)[aid];
        out[b * 2 + 0] = red[0][0] + red[1][0] + red[2][0] + red[3][0] + bias2.x;
        out[b * 2 + 1] = red[0][1] + red[1][1] + red[2][1] + red[3][1] + bias2.y;
    }
}

extern "C" void kernel_launch(void* const* d_in, const int* in_sizes, int n_in,
                              void* d_out, int out_size, void* d_ws, size_t ws_size,
                              hipStream_t stream) {
    const float* X          = (const float*)d_in[0];
    const int*   aspect_ids = (const int*)d_in[1];
    const float* W1_embs    = (const float*)d_in[2];
    const float* b1_embs    = (const float*)d_in[3];
    const float* W2_embs    = (const float*)d_in[4];
    const float* b2_embs    = (const float*)d_in[5];
    float*       out        = (float*)d_out;

    const int Brt = in_sizes[0] / D;
    const int na  = in_sizes[2] / (D * H);

    if (Brt != NB || na != NA || ws_size < WS_NEEDED) {
        aspect_mlp_fallback<<<Brt, 256, 0, stream>>>(
            X, aspect_ids, W1_embs, b1_embs, W2_embs, b2_embs, out);
        return;
    }

    unsigned short* part = (unsigned short*)d_ws;

    gemm1_kernel<<<dim3(NA, HSN, DKN), 256, 0, stream>>>(
        X, aspect_ids, W1_embs, b1_embs, part);
    finish_kernel<<<NB / 4, 256, 0, stream>>>(
        aspect_ids, part, W2_embs, b2_embs, out);
}

// Round 11
// 20.183 us; speedup vs baseline: 2.0735x; 1.3471x over previous
//
#include <hip/hip_runtime.h>

// MFMA aspect-grouped 2-layer MLP, 2 dispatches, in-LDS transpose.
//   gemm1:  grid (20 aspects, 4 col-slices, 8 d-slices) x 256 thr.
//           Ballot-scan aspect_ids -> sample list; W1 tile [96k][64c] fp32
//           loaded coalesced, converted+scattered ONCE to bf16 W1T_lds
//           [64c][96k] (k-contiguous); per 16-sample chunk: X slice staged as
//           bf16 [16][96], each wave computes 16 samples x 16 cols x 96k via
//           3 x mfma_f32_16x16x32_bf16 (6 ds_read_b128 total; layout verified
//           in R9), writes fp32 part[sample][dk][col] (+b1 at dk==0).
//   finish: per sample: sum 8 dk-partials, ReLU, x W2 + b2 -> out (R7-proven).

constexpr int D  = 768;
constexpr int H  = 256;
constexpr int NA = 20;
constexpr int NB = 1024;
constexpr int S  = 16;            // samples per chunk
constexpr int DKN = 8;            // d-slices
constexpr int KS  = D / DKN;      // 96 k per block
constexpr int HSN = 4;            // 64-col slices
constexpr int RW  = KS + 8;       // 104 shorts/row (208B, 16B-aligned)

constexpr size_t WS_NEEDED = (size_t)NB * DKN * H * 4;   // fp32 part: 8 MB

typedef __attribute__((ext_vector_type(8))) short short8v;  // 8 bf16
typedef __attribute__((ext_vector_type(4))) float f32x4;

__device__ __forceinline__ unsigned f2bf(float x) {   // RTN-even, low 16
    const unsigned u = __float_as_uint(x);
    return (u + 0x7FFFu + ((u >> 16) & 1u)) >> 16;
}

__global__ __launch_bounds__(256, 4) void gemm1_kernel(
    const float* __restrict__ X,
    const int*   __restrict__ aids,
    const float* __restrict__ W1,
    const float* __restrict__ b1,
    float*       __restrict__ part)    // [NB][DKN][H]
{
    __shared__ __align__(16) short w1t[64 * RW];   // bf16 W1T [64c][96k]
    __shared__ __align__(16) short xl[S * RW];     // bf16 X   [16s][96k]
    __shared__ int sidx[NB + S];
    __shared__ int n_sh;

    int* ai = reinterpret_cast<int*>(w1t);         // prologue overlay (4KB)

    const int t = threadIdx.x;
    const int w = t >> 6, l = t & 63;
    const int aid = blockIdx.x, hs = blockIdx.y, dk = blockIdx.z;

    ai[t]       = aids[t];
    ai[t + 256] = aids[t + 256];
    ai[t + 512] = aids[t + 512];
    ai[t + 768] = aids[t + 768];
    __syncthreads();

    // wave 0: stable ballot-scan -> full sample list, padded to x16
    if (w == 0) {
        int run = 0;
        for (int base = 0; base < NB; base += 64) {
            const int id = ai[base + l];
            const unsigned long long m = __ballot(id == aid);
            const int pre = run + __popcll(m & ((1ull << l) - 1));
            if (id == aid) sidx[pre] = base + l;
            run += __popcll(m);
        }
        if (run > 0) {
            const int last = sidx[run - 1];          // own-wave write, ordered
            const int npad = ((run + S - 1) / S) * S;
            if (l < S && run + l < npad) sidx[run + l] = last;
        }
        if (l == 0) n_sh = run;
    }
    __syncthreads();                    // ai dead from here
    const int n = n_sh;
    if (n == 0) return;                 // uniform exit

    // W1 tile -> bf16 transposed in LDS, ONE TIME.
    // i -> (k-pair kq, col-quad cq): coalesced f4 loads of rows k0,k0+1;
    // pack k-pairs per col, b32 scatter into w1t rows (one-time conflicts ok).
    {
        const float* W1s = W1 + (size_t)aid * D * H + (size_t)dk * KS * H + hs * 64;
        unsigned* w1u = reinterpret_cast<unsigned*>(w1t);   // row c at c*(RW/2)
        for (int i = t; i < (KS / 2) * 16; i += 256) {      // 768: 3 per thread
            const int kq = i >> 4, cq = i & 15;
            const int k0 = kq * 2;
            const float4 a = *reinterpret_cast<const float4*>(&W1s[(size_t)k0 * H + cq * 4]);
            const float4 b = *reinterpret_cast<const float4*>(&W1s[(size_t)(k0 + 1) * H + cq * 4]);
            w1u[(cq * 4 + 0) * (RW / 2) + kq] = f2bf(a.x) | (f2bf(b.x) << 16);
            w1u[(cq * 4 + 1) * (RW / 2) + kq] = f2bf(a.y) | (f2bf(b.y) << 16);
            w1u[(cq * 4 + 2) * (RW / 2) + kq] = f2bf(a.z) | (f2bf(b.z) << 16);
            w1u[(cq * 4 + 3) * (RW / 2) + kq] = f2bf(a.w) | (f2bf(b.w) << 16);
        }
    }
    // first in-loop __syncthreads covers w1t before any MFMA read.

    const int cg = l & 15, g = l >> 4;
    const short* xa = &xl[cg * RW + 8 * g];                 // A: row=sample=cg
    const short* wa = &w1t[(w * 16 + cg) * RW + 8 * g];     // B: col=cg (R9 map)
    const int gcol = hs * 64 + w * 16 + cg;
    const float b1v = (dk == 0) ? b1[(size_t)aid * H + gcol] : 0.f;

    for (int ch = 0; ch * S < n; ++ch) {
        // stage X chunk [16][96] as bf16 (f4 load + pack + b64 write)
        for (int i = t; i < S * (KS / 4); i += 256) {       // 384
            const int r = i / (KS / 4), q = i - r * (KS / 4);
            const float4 v = *reinterpret_cast<const float4*>(
                &X[(size_t)sidx[ch * S + r] * D + dk * KS + q * 4]);
            uint2 o;
            o.x = f2bf(v.x) | (f2bf(v.y) << 16);
            o.y = f2bf(v.z) | (f2bf(v.w) << 16);
            *reinterpret_cast<uint2*>(&xl[r * RW + q * 4]) = o;
        }
        __syncthreads();

        // 16 samples x 16 cols x 96 k per wave: 3 MFMA, 6 ds_read_b128
        f32x4 acc = {0.f, 0.f, 0.f, 0.f};
        #pragma unroll
        for (int kk = 0; kk < KS; kk += 32) {
            const short8v av = *reinterpret_cast<const short8v*>(xa + kk);
            const short8v bv = *reinterpret_cast<const short8v*>(wa + kk);
            acc = __builtin_amdgcn_mfma_f32_16x16x32_bf16(av, bv, acc, 0, 0, 0);
        }

        // D[row=4g+r][col=cg] (R9-verified); write fp32 partials
        const int cv = min(S, n - ch * S);
        #pragma unroll
        for (int r = 0; r < 4; ++r) {
            const int s = g * 4 + r;
            if (s < cv) {
                part[((size_t)sidx[ch * S + s] * DKN + dk) * H + gcol] = acc[r] + b1v;
            }
        }
        __syncthreads();               // protect xl before next restage
    }
}

__global__ __launch_bounds__(256) void finish_kernel(
    const int*   __restrict__ aids,
    const float* __restrict__ part,
    const float* __restrict__ W2,
    const float* __restrict__ b2,
    float*       __restrict__ out)
{
    const int w = threadIdx.x >> 6, l = threadIdx.x & 63;
    const int s = blockIdx.x * 4 + w;       // one sample per wave
    const int aid = aids[s];

    const float* ps = part + (size_t)s * DKN * H + l * 4;
    float4 v = {0, 0, 0, 0};
    #pragma unroll
    for (int dk = 0; dk < DKN; ++dk) {
        const float4 r = *reinterpret_cast<const float4*>(ps + dk * H);
        v.x += r.x; v.y += r.y; v.z += r.z; v.w += r.w;
    }
    float4 o;
    o.x = fmaxf(v.x, 0.f);
    o.y = fmaxf(v.y, 0.f);
    o.z = fmaxf(v.z, 0.f);
    o.w = fmaxf(v.w, 0.f);

    const float4* W2v = reinterpret_cast<const float4*>(&W2[(size_t)aid * H * 2 + l * 8]);
    const float4 w2a = W2v[0], w2b = W2v[1];
    float p0 = o.x * w2a.x + o.y * w2a.z + o.z * w2b.x + o.w * w2b.z;
    float p1 = o.x * w2a.y + o.y * w2a.w + o.z * w2b.y + o.w * w2b.w;
    #pragma unroll
    for (int m = 1; m < 64; m <<= 1) {
        p0 += __shfl_xor(p0, m, 64);
        p1 += __shfl_xor(p1, m, 64);
    }
    if (l == 0) {
        const float2 bias2 = reinterpret_cast<const float2*>(b2)[aid];
        reinterpret_cast<float2*>(out)[s] = make_float2(p0 + bias2.x, p1 + bias2.y);
    }
}

// ---------------- fallback (round-1 monolithic kernel) ----------------
__global__ __launch_bounds__(256, 4) void aspect_mlp_fallback(
    const float* __restrict__ X, const int* __restrict__ aspect_ids,
    const float* __restrict__ W1_embs, const float* __restrict__ b1_embs,
    const float* __restrict__ W2_embs, const float* __restrict__ b2_embs,
    float* __restrict__ out)
{
    __shared__ float xs[D];
    __shared__ float pl[4][H];
    __shared__ float red[4][2];
    const int b = blockIdx.x, t = threadIdx.x, w = t >> 6, l = t & 63;
    const int aid = aspect_ids[b];
    const float4* Xr = reinterpret_cast<const float4*>(X + (size_t)b * D);
    if (t < D / 4) reinterpret_cast<float4*>(xs)[t] = Xr[t];
    __syncthreads();
    const float4* W1v = reinterpret_cast<const float4*>(W1_embs + (size_t)aid * (D * H));
    float4 acc = make_float4(0.f, 0.f, 0.f, 0.f);
    const int d0 = w * (D / 4);
    for (int d = d0; d < d0 + D / 4; ++d) {
        const float xv = xs[d];
        const float4 wv = W1v[d * (H / 4) + l];
        acc.x = fmaf(xv, wv.x, acc.x); acc.y = fmaf(xv, wv.y, acc.y);
        acc.z = fmaf(xv, wv.z, acc.z); acc.w = fmaf(xv, wv.w, acc.w);
    }
    reinterpret_cast<float4*>(pl[w])[l] = acc;
    __syncthreads();
    const float o = fmaxf(pl[0][t] + pl[1][t] + pl[2][t] + pl[3][t] + b1_embs[aid * H + t], 0.f);
    const float2 w2 = reinterpret_cast<const float2*>(W2_embs)[aid * H + t];
    float p0 = o * w2.x, p1 = o * w2.y;
    for (int s = 32; s; s >>= 1) { p0 += __shfl_xor(p0, s, 64); p1 += __shfl_xor(p1, s, 64); }
    if (l == 0) { red[w][0] = p0; red[w][1] = p1; }
    __syncthreads();
    if (t == 0) {
        const float2 bias2 = reinterpret_cast<const float2*>(b2_embs)[aid];
        out[b * 2 + 0] = red[0][0] + red[1][0] + red[2][0] + red[3][0] + bias2.x;
        out[b * 2 + 1] = red[0][1] + red[1][1] + red[2][1] + red[3][1] + bias2.y;
    }
}

extern "C" void kernel_launch(void* const* d_in, const int* in_sizes, int n_in,
                              void* d_out, int out_size, void* d_ws, size_t ws_size,
                              hipStream_t stream) {
    const float* X          = (const float*)d_in[0];
    const int*   aspect_ids = (const int*)d_in[1];
    const float* W1_embs    = (const float*)d_in[2];
    const float* b1_embs    = (const float*)d_in[3];
    const float* W2_embs    = (const float*)d_in[4];
    const float* b2_embs    = (const float*)d_in[5];
    float*       out        = (float*)d_out;

    const int Brt = in_sizes[0] / D;
    const int na  = in_sizes[2] / (D * H);

    if (Brt != NB || na != NA || ws_size < WS_NEEDED) {
        aspect_mlp_fallback<<<Brt, 256, 0, stream>>>(
            X, aspect_ids, W1_embs, b1_embs, W2_embs, b2_embs, out);
        return;
    }

    float* part = (float*)d_ws;

    gemm1_kernel<<<dim3(NA, HSN, DKN), 256, 0, stream>>>(
        X, aspect_ids, W1_embs, b1_embs, part);
    finish_kernel<<<NB / 4, 256, 0, stream>>>(
        aspect_ids, part, W2_embs, b2_embs, out);
}

// Round 12
// 17.235 us; speedup vs baseline: 2.4281x; 1.1710x over previous
//
#include <hip/hip_runtime.h>

// MFMA aspect-grouped 2-layer MLP, 2 dispatches, in-LDS transpose.
//   gemm1:  grid (20 aspects, 4 col-slices, 8 d-slices) x 256 thr.
//           PROLOGUE OVERLAPPED: wave 0 ballot-scans aspect_ids (read straight
//           from global) -> sidx (padded to x32) while waves 1-3 convert+
//           transpose the W1 tile [96k][64c] fp32 -> bf16 W1T_lds [64c][96k];
//           one barrier. Per 32-sample chunk: X staged as bf16 [32][96], each
//           wave computes 32 samples x 16 cols x 96k via 6 x
//           mfma_f32_16x16x32_bf16 (R9/R11-verified layout), writes bf16
//           part[sample][dk][col] (+b1 folded at dk==0).
//   finish: per sample: sum 8 bf16 dk-partials (fp32), ReLU, x W2 + b2 -> out.

constexpr int D  = 768;
constexpr int H  = 256;
constexpr int NA = 20;
constexpr int NB = 1024;
constexpr int S  = 32;            // samples per chunk
constexpr int DKN = 8;            // d-slices
constexpr int KS  = D / DKN;      // 96 k per block
constexpr int HSN = 4;            // 64-col slices
constexpr int RW  = KS + 8;       // 104 shorts/row (208B, 16B-aligned)

constexpr size_t WS_NEEDED = (size_t)NB * DKN * H * 2;   // bf16 part: 4 MB

typedef __attribute__((ext_vector_type(8))) short short8v;  // 8 bf16
typedef __attribute__((ext_vector_type(4))) float f32x4;

__device__ __forceinline__ unsigned f2bf(float x) {   // RTN-even, low 16
    const unsigned u = __float_as_uint(x);
    return (u + 0x7FFFu + ((u >> 16) & 1u)) >> 16;
}
__device__ __forceinline__ float bflo(unsigned u) { return __uint_as_float(u << 16); }
__device__ __forceinline__ float bfhi(unsigned u) { return __uint_as_float(u & 0xFFFF0000u); }

__global__ __launch_bounds__(256, 4) void gemm1_kernel(
    const float* __restrict__ X,
    const int*   __restrict__ aids,
    const float* __restrict__ W1,
    const float* __restrict__ b1,
    unsigned short* __restrict__ part)   // bf16 [NB][DKN][H]
{
    __shared__ __align__(16) short w1t[64 * RW];   // bf16 W1T [64c][96k]
    __shared__ __align__(16) short xl[S * RW];     // bf16 X   [32s][96k]
    __shared__ int sidx[NB + S];
    __shared__ int n_sh;

    const int t = threadIdx.x;
    const int w = t >> 6, l = t & 63;
    const int aid = blockIdx.x, hs = blockIdx.y, dk = blockIdx.z;

    if (w == 0) {
        // wave 0: stable ballot-scan straight from global -> sidx, pad to x32
        int run = 0;
        #pragma unroll
        for (int base = 0; base < NB; base += 64) {
            const int id = aids[base + l];
            const unsigned long long m = __ballot(id == aid);
            const int pre = run + __popcll(m & ((1ull << l) - 1));
            if (id == aid) sidx[pre] = base + l;
            run += __popcll(m);
        }
        if (run > 0) {
            const int last = sidx[run - 1];          // own-wave write, ordered
            const int npad = ((run + S - 1) / S) * S;
            if (l < S && run + l < npad) sidx[run + l] = last;
        }
        if (l == 0) n_sh = run;
    } else {
        // waves 1-3: W1 tile -> bf16 transposed in LDS (concurrent with scan).
        // i -> (k-pair kq, col-quad cq): coalesced f4 loads of rows k0,k0+1;
        // pack k-pairs per col, b32 scatter (one-time conflicts ok).
        const float* W1s = W1 + (size_t)aid * D * H + (size_t)dk * KS * H + hs * 64;
        unsigned* w1u = reinterpret_cast<unsigned*>(w1t);   // row c at c*(RW/2)
        for (int i = t - 64; i < (KS / 2) * 16; i += 192) { // 768 iters, 4 each
            const int kq = i >> 4, cq = i & 15;
            const int k0 = kq * 2;
            const float4 a = *reinterpret_cast<const float4*>(&W1s[(size_t)k0 * H + cq * 4]);
            const float4 b = *reinterpret_cast<const float4*>(&W1s[(size_t)(k0 + 1) * H + cq * 4]);
            w1u[(cq * 4 + 0) * (RW / 2) + kq] = f2bf(a.x) | (f2bf(b.x) << 16);
            w1u[(cq * 4 + 1) * (RW / 2) + kq] = f2bf(a.y) | (f2bf(b.y) << 16);
            w1u[(cq * 4 + 2) * (RW / 2) + kq] = f2bf(a.z) | (f2bf(b.z) << 16);
            w1u[(cq * 4 + 3) * (RW / 2) + kq] = f2bf(a.w) | (f2bf(b.w) << 16);
        }
    }
    __syncthreads();
    const int n = n_sh;
    if (n == 0) return;                 // uniform exit

    const int cg = l & 15, g = l >> 4;
    const short* xa0 = &xl[cg * RW + 8 * g];            // A tile: samples 0-15
    const short* xa1 = &xl[(16 + cg) * RW + 8 * g];     // A tile: samples 16-31
    const short* wa  = &w1t[(w * 16 + cg) * RW + 8 * g];
    const int gcol = hs * 64 + w * 16 + cg;
    const float b1v = (dk == 0) ? b1[(size_t)aid * H + gcol] : 0.f;

    for (int ch = 0; ch * S < n; ++ch) {
        // stage X chunk [32][96] as bf16 (f4 load + pack + b64 write)
        for (int i = t; i < S * (KS / 4); i += 256) {       // 768 iters, 3 each
            const int r = i / (KS / 4), q = i - r * (KS / 4);
            const float4 v = *reinterpret_cast<const float4*>(
                &X[(size_t)sidx[ch * S + r] * D + dk * KS + q * 4]);
            uint2 o;
            o.x = f2bf(v.x) | (f2bf(v.y) << 16);
            o.y = f2bf(v.z) | (f2bf(v.w) << 16);
            *reinterpret_cast<uint2*>(&xl[r * RW + q * 4]) = o;
        }
        __syncthreads();

        // 32 samples x 16 cols x 96 k per wave: 6 MFMA, 12 ds_read_b128
        f32x4 acc0 = {0.f, 0.f, 0.f, 0.f}, acc1 = {0.f, 0.f, 0.f, 0.f};
        #pragma unroll
        for (int kk = 0; kk < KS; kk += 32) {
            const short8v bv = *reinterpret_cast<const short8v*>(wa + kk);
            acc0 = __builtin_amdgcn_mfma_f32_16x16x32_bf16(
                *reinterpret_cast<const short8v*>(xa0 + kk), bv, acc0, 0, 0, 0);
            acc1 = __builtin_amdgcn_mfma_f32_16x16x32_bf16(
                *reinterpret_cast<const short8v*>(xa1 + kk), bv, acc1, 0, 0, 0);
        }

        // D[row=4g+r][col=cg]; write bf16 partials (guarded: cv)
        const int cv = min(S, n - ch * S);
        #pragma unroll
        for (int r = 0; r < 4; ++r) {
            const int s0 = g * 4 + r;
            if (s0 < cv) {
                part[((size_t)sidx[ch * S + s0] * DKN + dk) * H + gcol] =
                    (unsigned short)f2bf(acc0[r] + b1v);
            }
            const int s1 = 16 + g * 4 + r;
            if (s1 < cv) {
                part[((size_t)sidx[ch * S + s1] * DKN + dk) * H + gcol] =
                    (unsigned short)f2bf(acc1[r] + b1v);
            }
        }
        __syncthreads();               // protect xl before next restage
    }
}

__global__ __launch_bounds__(256) void finish_kernel(
    const int*            __restrict__ aids,
    const unsigned short* __restrict__ part,
    const float*          __restrict__ W2,
    const float*          __restrict__ b2,
    float*                __restrict__ out)
{
    const int w = threadIdx.x >> 6, l = threadIdx.x & 63;
    const int s = blockIdx.x * 4 + w;       // one sample per wave
    const int aid = aids[s];

    const unsigned short* ps = part + (size_t)s * DKN * H + l * 4;
    float4 v = {0, 0, 0, 0};
    #pragma unroll
    for (int dk = 0; dk < DKN; ++dk) {
        const uint2 r = *reinterpret_cast<const uint2*>(ps + dk * H);
        v.x += bflo(r.x); v.y += bfhi(r.x);
        v.z += bflo(r.y); v.w += bfhi(r.y);
    }
    float4 o;
    o.x = fmaxf(v.x, 0.f);
    o.y = fmaxf(v.y, 0.f);
    o.z = fmaxf(v.z, 0.f);
    o.w = fmaxf(v.w, 0.f);

    const float4* W2v = reinterpret_cast<const float4*>(&W2[(size_t)aid * H * 2 + l * 8]);
    const float4 w2a = W2v[0], w2b = W2v[1];
    float p0 = o.x * w2a.x + o.y * w2a.z + o.z * w2b.x + o.w * w2b.z;
    float p1 = o.x * w2a.y + o.y * w2a.w + o.z * w2b.y + o.w * w2b.w;
    #pragma unroll
    for (int m = 1; m < 64; m <<= 1) {
        p0 += __shfl_xor(p0, m, 64);
        p1 += __shfl_xor(p1, m, 64);
    }
    if (l == 0) {
        const float2 bias2 = reinterpret_cast<const float2*>(b2)[aid];
        reinterpret_cast<float2*>(out)[s] = make_float2(p0 + bias2.x, p1 + bias2.y);
    }
}

// ---------------- fallback (round-1 monolithic kernel) ----------------
__global__ __launch_bounds__(256, 4) void aspect_mlp_fallback(
    const float* __restrict__ X, const int* __restrict__ aspect_ids,
    const float* __restrict__ W1_embs, const float* __restrict__ b1_embs,
    const float* __restrict__ W2_embs, const float* __restrict__ b2_embs,
    float* __restrict__ out)
{
    __shared__ float xs[D];
    __shared__ float pl[4][H];
    __shared__ float red[4][2];
    const int b = blockIdx.x, t = threadIdx.x, w = t >> 6, l = t & 63;
    const int aid = aspect_ids[b];
    const float4* Xr = reinterpret_cast<const float4*>(X + (size_t)b * D);
    if (t < D / 4) reinterpret_cast<float4*>(xs)[t] = Xr[t];
    __syncthreads();
    const float4* W1v = reinterpret_cast<const float4*>(W1_embs + (size_t)aid * (D * H));
    float4 acc = make_float4(0.f, 0.f, 0.f, 0.f);
    const int d0 = w * (D / 4);
    for (int d = d0; d < d0 + D / 4; ++d) {
        const float xv = xs[d];
        const float4 wv = W1v[d * (H / 4) + l];
        acc.x = fmaf(xv, wv.x, acc.x); acc.y = fmaf(xv, wv.y, acc.y);
        acc.z = fmaf(xv, wv.z, acc.z); acc.w = fmaf(xv, wv.w, acc.w);
    }
    reinterpret_cast<float4*>(pl[w])[l] = acc;
    __syncthreads();
    const float o = fmaxf(pl[0][t] + pl[1][t] + pl[2][t] + pl[3][t] + b1_embs[aid * H + t], 0.f);
    const float2 w2 = reinterpret_cast<const float2*>(W2_embs)[aid * H + t];
    float p0 = o * w2.x, p1 = o * w2.y;
    for (int s = 32; s; s >>= 1) { p0 += __shfl_xor(p0, s, 64); p1 += __shfl_xor(p1, s, 64); }
    if (l == 0) { red[w][0] = p0; red[w][1] = p1; }
    __syncthreads();
    if (t == 0) {
        const float2 bias2 = reinterpret_cast<const float2*>(b2_embs)[aid];
        out[b * 2 + 0] = red[0][0] + red[1][0] + red[2][0] + red[3][0] + bias2.x;
        out[b * 2 + 1] = red[0][1] + red[1][1] + red[2][1] + red[3][1] + bias2.y;
    }
}

extern "C" void kernel_launch(void* const* d_in, const int* in_sizes, int n_in,
                              void* d_out, int out_size, void* d_ws, size_t ws_size,
                              hipStream_t stream) {
    const float* X          = (const float*)d_in[0];
    const int*   aspect_ids = (const int*)d_in[1];
    const float* W1_embs    = (const float*)d_in[2];
    const float* b1_embs    = (const float*)d_in[3];
    const float* W2_embs    = (const float*)d_in[4];
    const float* b2_embs    = (const float*)d_in[5];
    float*       out        = (float*)d_out;

    const int Brt = in_sizes[0] / D;
    const int na  = in_sizes[2] / (D * H);

    if (Brt != NB || na != NA || ws_size < WS_NEEDED) {
        aspect_mlp_fallback<<<Brt, 256, 0, stream>>>(
            X, aspect_ids, W1_embs, b1_embs, W2_embs, b2_embs, out);
        return;
    }

    unsigned short* part = (unsigned short*)d_ws;

    gemm1_kernel<<<dim3(NA, HSN, DKN), 256, 0, stream>>>(
        X, aspect_ids, W1_embs, b1_embs, part);
    finish_kernel<<<NB / 4, 256, 0, stream>>>(
        aspect_ids, part, W2_embs, b2_embs, out);
}

// Round 13
// 15.823 us; speedup vs baseline: 2.6448x; 1.0893x over previous
//
#include <hip/hip_runtime.h>

// MFMA aspect-grouped 2-layer MLP, 2 dispatches, in-LDS transpose.
//   gemm1:  grid (20 aspects, 4 col-slices, 8 d-slices) x 256 thr.
//           Wave 0 ballot-scans aspect_ids -> sidx (padded to x64) while
//           waves 1-3 convert+transpose W1 tile [96k][64c] fp32 -> bf16
//           W1T_lds [64c][96k]; one barrier. S=64: nearly every aspect is a
//           SINGLE chunk -> one X stage [64][96] bf16, 2 barriers total.
//           Each wave: 4 sample-tiles x 16 cols x 96k = 12 MFMA with B-frag
//           reuse (3 B + 12 A ds_read_b128). bf16 part[sample][dk][col]
//           (+b1 folded at dk==0).
//   finish: per sample: sum 8 bf16 dk-partials (fp32), ReLU, x W2 + b2 -> out.

constexpr int D  = 768;
constexpr int H  = 256;
constexpr int NA = 20;
constexpr int NB = 1024;
constexpr int S  = 64;            // samples per chunk (aspects avg ~51 -> 1 chunk)
constexpr int DKN = 8;            // d-slices
constexpr int KS  = D / DKN;      // 96 k per block
constexpr int HSN = 4;            // 64-col slices
constexpr int RW  = KS + 8;       // 104 shorts/row (208B, 16B-aligned)

constexpr size_t WS_NEEDED = (size_t)NB * DKN * H * 2;   // bf16 part: 4 MB

typedef __attribute__((ext_vector_type(8))) short short8v;  // 8 bf16
typedef __attribute__((ext_vector_type(4))) float f32x4;

__device__ __forceinline__ unsigned f2bf(float x) {   // RTN-even, low 16
    const unsigned u = __float_as_uint(x);
    return (u + 0x7FFFu + ((u >> 16) & 1u)) >> 16;
}
__device__ __forceinline__ float bflo(unsigned u) { return __uint_as_float(u << 16); }
__device__ __forceinline__ float bfhi(unsigned u) { return __uint_as_float(u & 0xFFFF0000u); }

__global__ __launch_bounds__(256, 4) void gemm1_kernel(
    const float* __restrict__ X,
    const int*   __restrict__ aids,
    const float* __restrict__ W1,
    const float* __restrict__ b1,
    unsigned short* __restrict__ part)   // bf16 [NB][DKN][H]
{
    __shared__ __align__(16) short w1t[64 * RW];   // bf16 W1T [64c][96k]
    __shared__ __align__(16) short xl[S * RW];     // bf16 X   [64s][96k]
    __shared__ int sidx[NB + S];
    __shared__ int n_sh;

    const int t = threadIdx.x;
    const int w = t >> 6, l = t & 63;
    const int aid = blockIdx.x, hs = blockIdx.y, dk = blockIdx.z;

    if (w == 0) {
        // wave 0: stable ballot-scan straight from global -> sidx, pad to x64
        int run = 0;
        #pragma unroll
        for (int base = 0; base < NB; base += 64) {
            const int id = aids[base + l];
            const unsigned long long m = __ballot(id == aid);
            const int pre = run + __popcll(m & ((1ull << l) - 1));
            if (id == aid) sidx[pre] = base + l;
            run += __popcll(m);
        }
        if (run > 0) {
            const int last = sidx[run - 1];          // own-wave write, ordered
            const int npad = ((run + S - 1) / S) * S;
            if (run + l < npad) sidx[run + l] = last;   // l covers up to 63 pads
        }
        if (l == 0) n_sh = run;
    } else {
        // waves 1-3: W1 tile -> bf16 transposed in LDS (concurrent with scan).
        const float* W1s = W1 + (size_t)aid * D * H + (size_t)dk * KS * H + hs * 64;
        unsigned* w1u = reinterpret_cast<unsigned*>(w1t);   // row c at c*(RW/2)
        for (int i = t - 64; i < (KS / 2) * 16; i += 192) { // 768 iters, 4 each
            const int kq = i >> 4, cq = i & 15;
            const int k0 = kq * 2;
            const float4 a = *reinterpret_cast<const float4*>(&W1s[(size_t)k0 * H + cq * 4]);
            const float4 b = *reinterpret_cast<const float4*>(&W1s[(size_t)(k0 + 1) * H + cq * 4]);
            w1u[(cq * 4 + 0) * (RW / 2) + kq] = f2bf(a.x) | (f2bf(b.x) << 16);
            w1u[(cq * 4 + 1) * (RW / 2) + kq] = f2bf(a.y) | (f2bf(b.y) << 16);
            w1u[(cq * 4 + 2) * (RW / 2) + kq] = f2bf(a.z) | (f2bf(b.z) << 16);
            w1u[(cq * 4 + 3) * (RW / 2) + kq] = f2bf(a.w) | (f2bf(b.w) << 16);
        }
    }
    __syncthreads();
    const int n = n_sh;
    if (n == 0) return;                 // uniform exit

    const int cg = l & 15, g = l >> 6 ? 0 : (l >> 4);   // (l>>4) in 0..3
    const short* wa = &w1t[(w * 16 + cg) * RW + 8 * (l >> 4)];
    const int gcol = hs * 64 + w * 16 + cg;
    const float b1v = (dk == 0) ? b1[(size_t)aid * H + gcol] : 0.f;

    for (int ch = 0; ch * S < n; ++ch) {
        // stage X chunk [64][96] as bf16 (f4 load + pack + b64 write)
        for (int i = t; i < S * (KS / 4); i += 256) {       // 1536 iters, 6 each
            const int r = i / (KS / 4), q = i - r * (KS / 4);
            const float4 v = *reinterpret_cast<const float4*>(
                &X[(size_t)sidx[ch * S + r] * D + dk * KS + q * 4]);
            uint2 o;
            o.x = f2bf(v.x) | (f2bf(v.y) << 16);
            o.y = f2bf(v.z) | (f2bf(v.w) << 16);
            *reinterpret_cast<uint2*>(&xl[r * RW + q * 4]) = o;
        }
        __syncthreads();

        // 64 samples x 16 cols x 96k per wave: 12 MFMA, 3 B + 12 A ds_reads
        const int gq = l >> 4;
        f32x4 acc0 = {0,0,0,0}, acc1 = {0,0,0,0}, acc2 = {0,0,0,0}, acc3 = {0,0,0,0};
        #pragma unroll
        for (int ks = 0; ks < 3; ++ks) {
            const short8v bv = *reinterpret_cast<const short8v*>(wa + ks * 32);
            const int kof = ks * 32 + 8 * gq;
            acc0 = __builtin_amdgcn_mfma_f32_16x16x32_bf16(
                *reinterpret_cast<const short8v*>(&xl[(cg)      * RW + kof]), bv, acc0, 0, 0, 0);
            acc1 = __builtin_amdgcn_mfma_f32_16x16x32_bf16(
                *reinterpret_cast<const short8v*>(&xl[(16 + cg) * RW + kof]), bv, acc1, 0, 0, 0);
            acc2 = __builtin_amdgcn_mfma_f32_16x16x32_bf16(
                *reinterpret_cast<const short8v*>(&xl[(32 + cg) * RW + kof]), bv, acc2, 0, 0, 0);
            acc3 = __builtin_amdgcn_mfma_f32_16x16x32_bf16(
                *reinterpret_cast<const short8v*>(&xl[(48 + cg) * RW + kof]), bv, acc3, 0, 0, 0);
        }

        // D[row=4g+r][col=cg]; write bf16 partials (guarded: cv)
        const int cv = min(S, n - ch * S);
        #pragma unroll
        for (int r = 0; r < 4; ++r) {
            const int s0 = gq * 4 + r;
            if (s0 < cv)
                part[((size_t)sidx[ch * S + s0] * DKN + dk) * H + gcol] =
                    (unsigned short)f2bf(acc0[r] + b1v);
            const int s1 = 16 + gq * 4 + r;
            if (s1 < cv)
                part[((size_t)sidx[ch * S + s1] * DKN + dk) * H + gcol] =
                    (unsigned short)f2bf(acc1[r] + b1v);
            const int s2 = 32 + gq * 4 + r;
            if (s2 < cv)
                part[((size_t)sidx[ch * S + s2] * DKN + dk) * H + gcol] =
                    (unsigned short)f2bf(acc2[r] + b1v);
            const int s3 = 48 + gq * 4 + r;
            if (s3 < cv)
                part[((size_t)sidx[ch * S + s3] * DKN + dk) * H + gcol] =
                    (unsigned short)f2bf(acc3[r] + b1v);
        }
        __syncthreads();               // protect xl before next restage (rare)
    }
}

__global__ __launch_bounds__(256) void finish_kernel(
    const int*            __restrict__ aids,
    const unsigned short* __restrict__ part,
    const float*          __restrict__ W2,
    const float*          __restrict__ b2,
    float*                __restrict__ out)
{
    const int w = threadIdx.x >> 6, l = threadIdx.x & 63;
    const int s = blockIdx.x * 4 + w;       // one sample per wave
    const int aid = aids[s];

    const unsigned short* ps = part + (size_t)s * DKN * H + l * 4;
    float4 v = {0, 0, 0, 0};
    #pragma unroll
    for (int dk = 0; dk < DKN; ++dk) {
        const uint2 r = *reinterpret_cast<const uint2*>(ps + dk * H);
        v.x += bflo(r.x); v.y += bfhi(r.x);
        v.z += bflo(r.y); v.w += bfhi(r.y);
    }
    float4 o;
    o.x = fmaxf(v.x, 0.f);
    o.y = fmaxf(v.y, 0.f);
    o.z = fmaxf(v.z, 0.f);
    o.w = fmaxf(v.w, 0.f);

    const float4* W2v = reinterpret_cast<const float4*>(&W2[(size_t)aid * H * 2 + l * 8]);
    const float4 w2a = W2v[0], w2b = W2v[1];
    float p0 = o.x * w2a.x + o.y * w2a.z + o.z * w2b.x + o.w * w2b.z;
    float p1 = o.x * w2a.y + o.y * w2a.w + o.z * w2b.y + o.w * w2b.w;
    #pragma unroll
    for (int m = 1; m < 64; m <<= 1) {
        p0 += __shfl_xor(p0, m, 64);
        p1 += __shfl_xor(p1, m, 64);
    }
    if (l == 0) {
        const float2 bias2 = reinterpret_cast<const float2*>(b2)[aid];
        reinterpret_cast<float2*>(out)[s] = make_float2(p0 + bias2.x, p1 + bias2.y);
    }
}

// ---------------- fallback (round-1 monolithic kernel) ----------------
__global__ __launch_bounds__(256, 4) void aspect_mlp_fallback(
    const float* __restrict__ X, const int* __restrict__ aspect_ids,
    const float* __restrict__ W1_embs, const float* __restrict__ b1_embs,
    const float* __restrict__ W2_embs, const float* __restrict__ b2_embs,
    float* __restrict__ out)
{
    __shared__ float xs[D];
    __shared__ float pl[4][H];
    __shared__ float red[4][2];
    const int b = blockIdx.x, t = threadIdx.x, w = t >> 6, l = t & 63;
    const int aid = aspect_ids[b];
    const float4* Xr = reinterpret_cast<const float4*>(X + (size_t)b * D);
    if (t < D / 4) reinterpret_cast<float4*>(xs)[t] = Xr[t];
    __syncthreads();
    const float4* W1v = reinterpret_cast<const float4*>(W1_embs + (size_t)aid * (D * H));
    float4 acc = make_float4(0.f, 0.f, 0.f, 0.f);
    const int d0 = w * (D / 4);
    for (int d = d0; d < d0 + D / 4; ++d) {
        const float xv = xs[d];
        const float4 wv = W1v[d * (H / 4) + l];
        acc.x = fmaf(xv, wv.x, acc.x); acc.y = fmaf(xv, wv.y, acc.y);
        acc.z = fmaf(xv, wv.z, acc.z); acc.w = fmaf(xv, wv.w, acc.w);
    }
    reinterpret_cast<float4*>(pl[w])[l] = acc;
    __syncthreads();
    const float o = fmaxf(pl[0][t] + pl[1][t] + pl[2][t] + pl[3][t] + b1_embs[aid * H + t], 0.f);
    const float2 w2 = reinterpret_cast<const float2*>(W2_embs)[aid * H + t];
    float p0 = o * w2.x, p1 = o * w2.y;
    for (int s = 32; s; s >>= 1) { p0 += __shfl_xor(p0, s, 64); p1 += __shfl_xor(p1, s, 64); }
    if (l == 0) { red[w][0] = p0; red[w][1] = p1; }
    __syncthreads();
    if (t == 0) {
        const float2 bias2 = reinterpret_cast<const float2*>(b2_embs)[aid];
        out[b * 2 + 0] = red[0][0] + red[1][0] + red[2][0] + red[3][0] + bias2.x;
        out[b * 2 + 1] = red[0][1] + red[1][1] + red[2][1] + red[3][1] + bias2.y;
    }
}

extern "C" void kernel_launch(void* const* d_in, const int* in_sizes, int n_in,
                              void* d_out, int out_size, void* d_ws, size_t ws_size,
                              hipStream_t stream) {
    const float* X          = (const float*)d_in[0];
    const int*   aspect_ids = (const int*)d_in[1];
    const float* W1_embs    = (const float*)d_in[2];
    const float* b1_embs    = (const float*)d_in[3];
    const float* W2_embs    = (const float*)d_in[4];
    const float* b2_embs    = (const float*)d_in[5];
    float*       out        = (float*)d_out;

    const int Brt = in_sizes[0] / D;
    const int na  = in_sizes[2] / (D * H);

    if (Brt != NB || na != NA || ws_size < WS_NEEDED) {
        aspect_mlp_fallback<<<Brt, 256, 0, stream>>>(
            X, aspect_ids, W1_embs, b1_embs, W2_embs, b2_embs, out);
        return;
    }

    unsigned short* part = (unsigned short*)d_ws;

    gemm1_kernel<<<dim3(NA, HSN, DKN), 256, 0, stream>>>(
        X, aspect_ids, W1_embs, b1_embs, part);
    finish_kernel<<<NB / 4, 256, 0, stream>>>(
        aspect_ids, part, W2_embs, b2_embs, out);
}

// Round 14
// 15.185 us; speedup vs baseline: 2.7558x; 1.0420x over previous
//
#include <hip/hip_runtime.h>

// MFMA aspect-grouped 2-layer MLP, 2 dispatches, in-LDS transpose.
//   gemm1:  flat 640-block grid, decoded hs=bid/160, p=bid%160, aid=p%20,
//           dk=p/20 -> the 4 hs-blocks of one (aid,dk) sit at id stride 160
//           (=0 mod 8): same XCD -> X slice reuse hits local L2.
//           Wave 0 ballot-scans aspect_ids (int4 loads, deterministic
//           interleaved order -- identical in every block) -> sidx (padded to
//           x64) while waves 1-3 transpose W1 tile [96k][64c] fp32 -> bf16
//           W1T_lds [64c][96k]; one barrier. One X stage [64][96] bf16;
//           each wave: 4 sample-tiles x 16 cols x 96k = 12 MFMA (3 B + 12 A
//           ds_read_b128). bf16 part[sample][dk][col] (+b1 at dk==0).
//   finish: 128 blocks; 2 samples/wave (32 lanes x 8 cols), uint4 part reads;
//           sum 8 dk-partials, ReLU, x W2 + b2 -> out.

constexpr int D  = 768;
constexpr int H  = 256;
constexpr int NA = 20;
constexpr int NB = 1024;
constexpr int S  = 64;            // samples per chunk (aspects avg ~51 -> 1 chunk)
constexpr int DKN = 8;            // d-slices
constexpr int KS  = D / DKN;      // 96 k per block
constexpr int HSN = 4;            // 64-col slices
constexpr int RW  = KS + 8;       // 104 shorts/row (208B, 16B-aligned)

constexpr size_t WS_NEEDED = (size_t)NB * DKN * H * 2;   // bf16 part: 4 MB

typedef __attribute__((ext_vector_type(8))) short short8v;  // 8 bf16
typedef __attribute__((ext_vector_type(4))) float f32x4;

__device__ __forceinline__ unsigned f2bf(float x) {   // RTN-even, low 16
    const unsigned u = __float_as_uint(x);
    return (u + 0x7FFFu + ((u >> 16) & 1u)) >> 16;
}
__device__ __forceinline__ float bflo(unsigned u) { return __uint_as_float(u << 16); }
__device__ __forceinline__ float bfhi(unsigned u) { return __uint_as_float(u & 0xFFFF0000u); }

__global__ __launch_bounds__(256, 4) void gemm1_kernel(
    const float* __restrict__ X,
    const int*   __restrict__ aids,
    const float* __restrict__ W1,
    const float* __restrict__ b1,
    unsigned short* __restrict__ part)   // bf16 [NB][DKN][H]
{
    __shared__ __align__(16) short w1t[64 * RW];   // bf16 W1T [64c][96k]
    __shared__ __align__(16) short xl[S * RW];     // bf16 X   [64s][96k]
    __shared__ int sidx[NB + S];
    __shared__ int n_sh;

    const int t = threadIdx.x;
    const int w = t >> 6, l = t & 63;
    const int bid = blockIdx.x;
    const int hs  = bid / 160;         // 0..3
    const int p   = bid - hs * 160;    // 0..159
    const int aid = p % NA;            // 0..19
    const int dk  = p / NA;            // 0..7

    if (w == 0) {
        // wave 0: ballot-scan, int4 loads. Order = interleaved (lane-major),
        // deterministic and IDENTICAL across all blocks -> consistent chunks.
        int run = 0;
        #pragma unroll
        for (int base = 0; base < NB; base += 256) {
            const int4 v = *reinterpret_cast<const int4*>(&aids[base + l * 4]);
            #pragma unroll
            for (int j = 0; j < 4; ++j) {
                const int id = (j == 0) ? v.x : (j == 1) ? v.y : (j == 2) ? v.z : v.w;
                const unsigned long long m = __ballot(id == aid);
                const int pre = run + __popcll(m & ((1ull << l) - 1));
                if (id == aid) sidx[pre] = base + l * 4 + j;
                run += __popcll(m);
            }
        }
        if (run > 0) {
            const int last = sidx[run - 1];          // own-wave write, ordered
            const int npad = ((run + S - 1) / S) * S;
            if (run + l < npad) sidx[run + l] = last;
        }
        if (l == 0) n_sh = run;
    } else {
        // waves 1-3: W1 tile -> bf16 transposed in LDS (concurrent with scan).
        const float* W1s = W1 + (size_t)aid * D * H + (size_t)dk * KS * H + hs * 64;
        unsigned* w1u = reinterpret_cast<unsigned*>(w1t);   // row c at c*(RW/2)
        for (int i = t - 64; i < (KS / 2) * 16; i += 192) { // 768 iters, 4 each
            const int kq = i >> 4, cq = i & 15;
            const int k0 = kq * 2;
            const float4 a = *reinterpret_cast<const float4*>(&W1s[(size_t)k0 * H + cq * 4]);
            const float4 b = *reinterpret_cast<const float4*>(&W1s[(size_t)(k0 + 1) * H + cq * 4]);
            w1u[(cq * 4 + 0) * (RW / 2) + kq] = f2bf(a.x) | (f2bf(b.x) << 16);
            w1u[(cq * 4 + 1) * (RW / 2) + kq] = f2bf(a.y) | (f2bf(b.y) << 16);
            w1u[(cq * 4 + 2) * (RW / 2) + kq] = f2bf(a.z) | (f2bf(b.z) << 16);
            w1u[(cq * 4 + 3) * (RW / 2) + kq] = f2bf(a.w) | (f2bf(b.w) << 16);
        }
    }
    __syncthreads();
    const int n = n_sh;
    if (n == 0) return;                 // uniform exit

    const int cg = l & 15, gq = l >> 4;
    const short* wa = &w1t[(w * 16 + cg) * RW + 8 * gq];
    const int gcol = hs * 64 + w * 16 + cg;
    const float b1v = (dk == 0) ? b1[(size_t)aid * H + gcol] : 0.f;

    for (int ch = 0; ch * S < n; ++ch) {
        // stage X chunk [64][96] as bf16 (f4 load + pack + b64 write)
        for (int i = t; i < S * (KS / 4); i += 256) {       // 1536 iters, 6 each
            const int r = i / (KS / 4), q = i - r * (KS / 4);
            const float4 v = *reinterpret_cast<const float4*>(
                &X[(size_t)sidx[ch * S + r] * D + dk * KS + q * 4]);
            uint2 o;
            o.x = f2bf(v.x) | (f2bf(v.y) << 16);
            o.y = f2bf(v.z) | (f2bf(v.w) << 16);
            *reinterpret_cast<uint2*>(&xl[r * RW + q * 4]) = o;
        }
        __syncthreads();

        // 64 samples x 16 cols x 96k per wave: 12 MFMA, 3 B + 12 A ds_reads
        f32x4 acc0 = {0,0,0,0}, acc1 = {0,0,0,0}, acc2 = {0,0,0,0}, acc3 = {0,0,0,0};
        #pragma unroll
        for (int ks = 0; ks < 3; ++ks) {
            const short8v bv = *reinterpret_cast<const short8v*>(wa + ks * 32);
            const int kof = ks * 32 + 8 * gq;
            acc0 = __builtin_amdgcn_mfma_f32_16x16x32_bf16(
                *reinterpret_cast<const short8v*>(&xl[(cg)      * RW + kof]), bv, acc0, 0, 0, 0);
            acc1 = __builtin_amdgcn_mfma_f32_16x16x32_bf16(
                *reinterpret_cast<const short8v*>(&xl[(16 + cg) * RW + kof]), bv, acc1, 0, 0, 0);
            acc2 = __builtin_amdgcn_mfma_f32_16x16x32_bf16(
                *reinterpret_cast<const short8v*>(&xl[(32 + cg) * RW + kof]), bv, acc2, 0, 0, 0);
            acc3 = __builtin_amdgcn_mfma_f32_16x16x32_bf16(
                *reinterpret_cast<const short8v*>(&xl[(48 + cg) * RW + kof]), bv, acc3, 0, 0, 0);
        }

        // D[row=4gq+r][col=cg]; write bf16 partials (guarded: cv)
        const int cv = min(S, n - ch * S);
        #pragma unroll
        for (int r = 0; r < 4; ++r) {
            const int s0 = gq * 4 + r;
            if (s0 < cv)
                part[((size_t)sidx[ch * S + s0] * DKN + dk) * H + gcol] =
                    (unsigned short)f2bf(acc0[r] + b1v);
            const int s1 = 16 + gq * 4 + r;
            if (s1 < cv)
                part[((size_t)sidx[ch * S + s1] * DKN + dk) * H + gcol] =
                    (unsigned short)f2bf(acc1[r] + b1v);
            const int s2 = 32 + gq * 4 + r;
            if (s2 < cv)
                part[((size_t)sidx[ch * S + s2] * DKN + dk) * H + gcol] =
                    (unsigned short)f2bf(acc2[r] + b1v);
            const int s3 = 48 + gq * 4 + r;
            if (s3 < cv)
                part[((size_t)sidx[ch * S + s3] * DKN + dk) * H + gcol] =
                    (unsigned short)f2bf(acc3[r] + b1v);
        }
        if ((ch + 1) * S < n) __syncthreads();   // only when another chunk follows
    }
}

__global__ __launch_bounds__(256) void finish_kernel(
    const int*            __restrict__ aids,
    const unsigned short* __restrict__ part,
    const float*          __restrict__ W2,
    const float*          __restrict__ b2,
    float*                __restrict__ out)
{
    const int w = threadIdx.x >> 6, l = threadIdx.x & 63;
    const int half = l >> 5;                 // 0/1: two samples per wave
    const int m = l & 31;                    // col-octet 0..31
    const int s = blockIdx.x * 8 + w * 2 + half;
    const int aid = aids[s];

    // accumulate 8 cols (m*8 .. m*8+7) over 8 dk-partials, uint4 loads
    const unsigned short* ps = part + (size_t)s * DKN * H + m * 8;
    float v[8] = {0, 0, 0, 0, 0, 0, 0, 0};
    #pragma unroll
    for (int dk = 0; dk < DKN; ++dk) {
        const uint4 r = *reinterpret_cast<const uint4*>(ps + dk * H);
        v[0] += bflo(r.x); v[1] += bfhi(r.x);
        v[2] += bflo(r.y); v[3] += bfhi(r.y);
        v[4] += bflo(r.z); v[5] += bfhi(r.z);
        v[6] += bflo(r.w); v[7] += bfhi(r.w);
    }

    // ReLU + layer-2 dot over these 8 cols
    const float4* W2v = reinterpret_cast<const float4*>(&W2[((size_t)aid * H + m * 8) * 2]);
    float p0 = 0.f, p1 = 0.f;
    #pragma unroll
    for (int c4 = 0; c4 < 4; ++c4) {
        const float4 wv = W2v[c4];           // cols 2c4 (x,y), 2c4+1 (z,w)
        const float o0 = fmaxf(v[c4 * 2 + 0], 0.f);
        const float o1 = fmaxf(v[c4 * 2 + 1], 0.f);
        p0 += o0 * wv.x + o1 * wv.z;
        p1 += o0 * wv.y + o1 * wv.w;
    }

    // reduce across the 32 lanes of this half-wave
    #pragma unroll
    for (int msk = 1; msk < 32; msk <<= 1) {
        p0 += __shfl_xor(p0, msk, 64);
        p1 += __shfl_xor(p1, msk, 64);
    }
    if (m == 0) {
        const float2 b2v = reinterpret_cast<const float2*>(b2)[aid];
        reinterpret_cast<float2*>(out)[s] = make_float2(p0 + b2v.x, p1 + b2v.y);
    }
}

// ---------------- fallback (round-1 monolithic kernel) ----------------
__global__ __launch_bounds__(256, 4) void aspect_mlp_fallback(
    const float* __restrict__ X, const int* __restrict__ aspect_ids,
    const float* __restrict__ W1_embs, const float* __restrict__ b1_embs,
    const float* __restrict__ W2_embs, const float* __restrict__ b2_embs,
    float* __restrict__ out)
{
    __shared__ float xs[D];
    __shared__ float pl[4][H];
    __shared__ float red[4][2];
    const int b = blockIdx.x, t = threadIdx.x, w = t >> 6, l = t & 63;
    const int aid = aspect_ids[b];
    const float4* Xr = reinterpret_cast<const float4*>(X + (size_t)b * D);
    if (t < D / 4) reinterpret_cast<float4*>(xs)[t] = Xr[t];
    __syncthreads();
    const float4* W1v = reinterpret_cast<const float4*>(W1_embs + (size_t)aid * (D * H));
    float4 acc = make_float4(0.f, 0.f, 0.f, 0.f);
    const int d0 = w * (D / 4);
    for (int d = d0; d < d0 + D / 4; ++d) {
        const float xv = xs[d];
        const float4 wv = W1v[d * (H / 4) + l];
        acc.x = fmaf(xv, wv.x, acc.x); acc.y = fmaf(xv, wv.y, acc.y);
        acc.z = fmaf(xv, wv.z, acc.z); acc.w = fmaf(xv, wv.w, acc.w);
    }
    reinterpret_cast<float4*>(pl[w])[l] = acc;
    __syncthreads();
    const float o = fmaxf(pl[0][t] + pl[1][t] + pl[2][t] + pl[3][t] + b1_embs[aid * H + t], 0.f);
    const float2 w2 = reinterpret_cast<const float2*>(W2_embs)[aid * H + t];
    float p0 = o * w2.x, p1 = o * w2.y;
    for (int s = 32; s; s >>= 1) { p0 += __shfl_xor(p0, s, 64); p1 += __shfl_xor(p1, s, 64); }
    if (l == 0) { red[w][0] = p0; red[w][1] = p1; }
    __syncthreads();
    if (t == 0) {
        const float2 bias2 = reinterpret_cast<const float2*>(b2_embs)[aid];
        out[b * 2 + 0] = red[0][0] + red[1][0] + red[2][0] + red[3][0] + bias2.x;
        out[b * 2 + 1] = red[0][1] + red[1][1] + red[2][1] + red[3][1] + bias2.y;
    }
}

extern "C" void kernel_launch(void* const* d_in, const int* in_sizes, int n_in,
                              void* d_out, int out_size, void* d_ws, size_t ws_size,
                              hipStream_t stream) {
    const float* X          = (const float*)d_in[0];
    const int*   aspect_ids = (const int*)d_in[1];
    const float* W1_embs    = (const float*)d_in[2];
    const float* b1_embs    = (const float*)d_in[3];
    const float* W2_embs    = (const float*)d_in[4];
    const float* b2_embs    = (const float*)d_in[5];
    float*       out        = (float*)d_out;

    const int Brt = in_sizes[0] / D;
    const int na  = in_sizes[2] / (D * H);

    if (Brt != NB || na != NA || ws_size < WS_NEEDED) {
        aspect_mlp_fallback<<<Brt, 256, 0, stream>>>(
            X, aspect_ids, W1_embs, b1_embs, W2_embs, b2_embs, out);
        return;
    }

    unsigned short* part = (unsigned short*)d_ws;

    gemm1_kernel<<<NA * HSN * DKN, 256, 0, stream>>>(
        X, aspect_ids, W1_embs, b1_embs, part);
    finish_kernel<<<NB / 8, 256, 0, stream>>>(
        aspect_ids, part, W2_embs, b2_embs, out);
}

// Round 16
// 14.560 us; speedup vs baseline: 2.8742x; 1.0430x over previous
//
#include <hip/hip_runtime.h>

// MFMA aspect-grouped 2-layer MLP, 2 dispatches, in-LDS transpose.
//   gemm1:  flat 640-block grid: hs=bid/80 (0..7, 32-col slice), p=bid%80,
//           aid=p%20, dk=p/20 (0..3, 192-k slice). hs stride 80 = 0 mod 8 ->
//           the 8 hs-blocks sharing one (aid,dk) X-slice sit on one XCD.
//           Wave 0 ballot-scans aspect_ids (int4, deterministic, identical in
//           every block) -> sidx (padded to x64) while waves 1-3 transpose
//           W1 tile [192k][32c] fp32 -> bf16 W1T_lds [32c][192k]; one barrier.
//           One X stage [64][192] bf16. Wave role: ct=w&1 col-tile, sh=w>>1
//           sample-half: 32 samples x 16 cols x 192k = 12 MFMA (6 B + 12 A
//           ds_read_b128). bf16 part[sample][dk][col] (+b1 at dk==0).
//   finish: 128 blocks; 2 samples/wave (32 lanes x 8 cols), uint4 part reads
//           (4 dk-partials), ReLU, x W2 + b2 -> out.

constexpr int D  = 768;
constexpr int H  = 256;
constexpr int NA = 20;
constexpr int NB = 1024;
constexpr int S  = 64;            // samples per chunk (aspects avg ~51 -> 1 chunk)
constexpr int DKN = 4;            // d-slices
constexpr int KS  = D / DKN;      // 192 k per block
constexpr int HSN = 8;            // 32-col slices
constexpr int RW  = KS + 8;       // 200 shorts/row (400B, 16B-aligned)

constexpr size_t WS_NEEDED = (size_t)NB * DKN * H * 2;   // bf16 part: 2 MB

typedef __attribute__((ext_vector_type(8))) short short8v;  // 8 bf16
typedef __attribute__((ext_vector_type(4))) float f32x4;

__device__ __forceinline__ unsigned f2bf(float x) {   // RTN-even, low 16
    const unsigned u = __float_as_uint(x);
    return (u + 0x7FFFu + ((u >> 16) & 1u)) >> 16;
}
__device__ __forceinline__ float bflo(unsigned u) { return __uint_as_float(u << 16); }
__device__ __forceinline__ float bfhi(unsigned u) { return __uint_as_float(u & 0xFFFF0000u); }

__global__ __launch_bounds__(256, 3) void gemm1_kernel(
    const float* __restrict__ X,
    const int*   __restrict__ aids,
    const float* __restrict__ W1,
    const float* __restrict__ b1,
    unsigned short* __restrict__ part)   // bf16 [NB][DKN][H]
{
    __shared__ __align__(16) short w1t[32 * RW];   // bf16 W1T [32c][192k]
    __shared__ __align__(16) short xl[S * RW];     // bf16 X   [64s][192k]
    __shared__ int sidx[NB + S];
    __shared__ int n_sh;

    const int t = threadIdx.x;
    const int w = t >> 6, l = t & 63;
    const int bid = blockIdx.x;
    const int hs  = bid / 80;          // 0..7, 32-col slice
    const int p   = bid - hs * 80;     // 0..79
    const int aid = p % NA;            // 0..19
    const int dk  = p / NA;            // 0..3, 192-k slice

    if (w == 0) {
        // wave 0: ballot-scan, int4 loads; deterministic interleaved order,
        // identical in every block.
        int run = 0;
        #pragma unroll
        for (int base = 0; base < NB; base += 256) {
            const int4 v = *reinterpret_cast<const int4*>(&aids[base + l * 4]);
            #pragma unroll
            for (int j = 0; j < 4; ++j) {
                const int id = (j == 0) ? v.x : (j == 1) ? v.y : (j == 2) ? v.z : v.w;
                const unsigned long long m = __ballot(id == aid);
                const int pre = run + __popcll(m & ((1ull << l) - 1));
                if (id == aid) sidx[pre] = base + l * 4 + j;
                run += __popcll(m);
            }
        }
        if (run > 0) {
            const int last = sidx[run - 1];          // own-wave write, ordered
            const int npad = ((run + S - 1) / S) * S;
            if (run + l < npad) sidx[run + l] = last;
        }
        if (l == 0) n_sh = run;
    } else {
        // waves 1-3: W1 tile [192k][32c] -> bf16 W1T_lds [32c][192k].
        // i -> (k-pair kq 0..95, col-quad cq 0..7); per k-row 8 f4 = 128B
        // contiguous (coalesced); b32 scatter into w1t rows.
        const float* W1s = W1 + (size_t)aid * D * H + (size_t)dk * KS * H + hs * 32;
        unsigned* w1u = reinterpret_cast<unsigned*>(w1t);   // row c at c*(RW/2)
        for (int i = t - 64; i < (KS / 2) * 8; i += 192) {  // 768 iters, 4 each
            const int kq = i >> 3, cq = i & 7;
            const int k0 = kq * 2;
            const float4 a = *reinterpret_cast<const float4*>(&W1s[(size_t)k0 * H + cq * 4]);
            const float4 b = *reinterpret_cast<const float4*>(&W1s[(size_t)(k0 + 1) * H + cq * 4]);
            w1u[(cq * 4 + 0) * (RW / 2) + kq] = f2bf(a.x) | (f2bf(b.x) << 16);
            w1u[(cq * 4 + 1) * (RW / 2) + kq] = f2bf(a.y) | (f2bf(b.y) << 16);
            w1u[(cq * 4 + 2) * (RW / 2) + kq] = f2bf(a.z) | (f2bf(b.z) << 16);
            w1u[(cq * 4 + 3) * (RW / 2) + kq] = f2bf(a.w) | (f2bf(b.w) << 16);
        }
    }
    __syncthreads();
    const int n = n_sh;
    if (n == 0) return;                 // uniform exit

    const int cg = l & 15, gq = l >> 4;
    const int ct = w & 1;               // col-tile within 32-col slice
    const int sh = w >> 1;              // sample-half (0: s 0..31, 1: s 32..63)
    const short* wa = &w1t[(ct * 16 + cg) * RW + 8 * gq];
    const int gcol = hs * 32 + ct * 16 + cg;
    const float b1v = (dk == 0) ? b1[(size_t)aid * H + gcol] : 0.f;

    for (int ch = 0; ch * S < n; ++ch) {
        // stage X chunk [64][192] as bf16 (f4 load + pack + b64 write)
        for (int i = t; i < S * (KS / 4); i += 256) {       // 3072 iters, 12 each
            const int r = i / (KS / 4), q = i - r * (KS / 4);
            const float4 v = *reinterpret_cast<const float4*>(
                &X[(size_t)sidx[ch * S + r] * D + dk * KS + q * 4]);
            uint2 o;
            o.x = f2bf(v.x) | (f2bf(v.y) << 16);
            o.y = f2bf(v.z) | (f2bf(v.w) << 16);
            *reinterpret_cast<uint2*>(&xl[r * RW + q * 4]) = o;
        }
        __syncthreads();

        // 32 samples x 16 cols x 192k per wave: 12 MFMA, 6 B + 12 A ds_reads
        f32x4 acc0 = {0,0,0,0}, acc1 = {0,0,0,0};
        #pragma unroll
        for (int ks = 0; ks < KS / 32; ++ks) {
            const short8v bv = *reinterpret_cast<const short8v*>(wa + ks * 32);
            const int kof = ks * 32 + 8 * gq;
            acc0 = __builtin_amdgcn_mfma_f32_16x16x32_bf16(
                *reinterpret_cast<const short8v*>(&xl[(sh * 32 + cg)      * RW + kof]), bv, acc0, 0, 0, 0);
            acc1 = __builtin_amdgcn_mfma_f32_16x16x32_bf16(
                *reinterpret_cast<const short8v*>(&xl[(sh * 32 + 16 + cg) * RW + kof]), bv, acc1, 0, 0, 0);
        }

        // D[row=4gq+r][col=cg]; write bf16 partials (guarded: cv)
        const int cv = min(S, n - ch * S);
        #pragma unroll
        for (int r = 0; r < 4; ++r) {
            const int s0 = sh * 32 + gq * 4 + r;
            if (s0 < cv)
                part[((size_t)sidx[ch * S + s0] * DKN + dk) * H + gcol] =
                    (unsigned short)f2bf(acc0[r] + b1v);
            const int s1 = sh * 32 + 16 + gq * 4 + r;
            if (s1 < cv)
                part[((size_t)sidx[ch * S + s1] * DKN + dk) * H + gcol] =
                    (unsigned short)f2bf(acc1[r] + b1v);
        }
        if ((ch + 1) * S < n) __syncthreads();   // only when another chunk follows
    }
}

__global__ __launch_bounds__(256) void finish_kernel(
    const int*            __restrict__ aids,
    const unsigned short* __restrict__ part,
    const float*          __restrict__ W2,
    const float*          __restrict__ b2,
    float*                __restrict__ out)
{
    const int w = threadIdx.x >> 6, l = threadIdx.x & 63;
    const int half = l >> 5;                 // 0/1: two samples per wave
    const int m = l & 31;                    // col-octet 0..31
    const int s = blockIdx.x * 8 + w * 2 + half;
    const int aid = aids[s];

    // accumulate 8 cols (m*8 .. m*8+7) over 4 dk-partials, uint4 loads
    const unsigned short* ps = part + (size_t)s * DKN * H + m * 8;
    float v[8] = {0, 0, 0, 0, 0, 0, 0, 0};
    #pragma unroll
    for (int dk = 0; dk < DKN; ++dk) {
        const uint4 r = *reinterpret_cast<const uint4*>(ps + dk * H);
        v[0] += bflo(r.x); v[1] += bfhi(r.x);
        v[2] += bflo(r.y); v[3] += bfhi(r.y);
        v[4] += bflo(r.z); v[5] += bfhi(r.z);
        v[6] += bflo(r.w); v[7] += bfhi(r.w);
    }

    // ReLU + layer-2 dot over these 8 cols
    const float4* W2v = reinterpret_cast<const float4*>(&W2[((size_t)aid * H + m * 8) * 2]);
    float p0 = 0.f, p1 = 0.f;
    #pragma unroll
    for (int c4 = 0; c4 < 4; ++c4) {
        const float4 wv = W2v[c4];           // cols 2c4 (x,y), 2c4+1 (z,w)
        const float o0 = fmaxf(v[c4 * 2 + 0], 0.f);
        const float o1 = fmaxf(v[c4 * 2 + 1], 0.f);
        p0 += o0 * wv.x + o1 * wv.z;
        p1 += o0 * wv.y + o1 * wv.w;
    }

    // reduce across the 32 lanes of this half-wave
    #pragma unroll
    for (int msk = 1; msk < 32; msk <<= 1) {
        p0 += __shfl_xor(p0, msk, 64);
        p1 += __shfl_xor(p1, msk, 64);
    }
    if (m == 0) {
        const float2 b2v = reinterpret_cast<const float2*>(b2)[aid];
        reinterpret_cast<float2*>(out)[s] = make_float2(p0 + b2v.x, p1 + b2v.y);
    }
}

// ---------------- fallback (round-1 monolithic kernel) ----------------
__global__ __launch_bounds__(256, 4) void aspect_mlp_fallback(
    const float* __restrict__ X, const int* __restrict__ aspect_ids,
    const float* __restrict__ W1_embs, const float* __restrict__ b1_embs,
    const float* __restrict__ W2_embs, const float* __restrict__ b2_embs,
    float* __restrict__ out)
{
    __shared__ float xs[D];
    __shared__ float pl[4][H];
    __shared__ float red[4][2];
    const int b = blockIdx.x, t = threadIdx.x, w = t >> 6, l = t & 63;
    const int aid = aspect_ids[b];
    const float4* Xr = reinterpret_cast<const float4*>(X + (size_t)b * D);
    if (t < D / 4) reinterpret_cast<float4*>(xs)[t] = Xr[t];
    __syncthreads();
    const float4* W1v = reinterpret_cast<const float4*>(W1_embs + (size_t)aid * (D * H));
    float4 acc = make_float4(0.f, 0.f, 0.f, 0.f);
    const int d0 = w * (D / 4);
    for (int d = d0; d < d0 + D / 4; ++d) {
        const float xv = xs[d];
        const float4 wv = W1v[d * (H / 4) + l];
        acc.x = fmaf(xv, wv.x, acc.x); acc.y = fmaf(xv, wv.y, acc.y);
        acc.z = fmaf(xv, wv.z, acc.z); acc.w = fmaf(xv, wv.w, acc.w);
    }
    reinterpret_cast<float4*>(pl[w])[l] = acc;
    __syncthreads();
    const float o = fmaxf(pl[0][t] + pl[1][t] + pl[2][t] + pl[3][t] + b1_embs[aid * H + t], 0.f);
    const float2 w2 = reinterpret_cast<const float2*>(W2_embs)[aid * H + t];
    float p0 = o * w2.x, p1 = o * w2.y;
    for (int s = 32; s; s >>= 1) { p0 += __shfl_xor(p0, s, 64); p1 += __shfl_xor(p1, s, 64); }
    if (l == 0) { red[w][0] = p0; red[w][1] = p1; }
    __syncthreads();
    if (t == 0) {
        const float2 bias2 = reinterpret_cast<const float2*>(b2_embs)[aid];
        out[b * 2 + 0] = red[0][0] + red[1][0] + red[2][0] + red[3][0] + bias2.x;
        out[b * 2 + 1] = red[0][1] + red[1][1] + red[2][1] + red[3][1] + bias2.y;
    }
}

extern "C" void kernel_launch(void* const* d_in, const int* in_sizes, int n_in,
                              void* d_out, int out_size, void* d_ws, size_t ws_size,
                              hipStream_t stream) {
    const float* X          = (const float*)d_in[0];
    const int*   aspect_ids = (const int*)d_in[1];
    const float* W1_embs    = (const float*)d_in[2];
    const float* b1_embs    = (const float*)d_in[3];
    const float* W2_embs    = (const float*)d_in[4];
    const float* b2_embs    = (const float*)d_in[5];
    float*       out        = (float*)d_out;

    const int Brt = in_sizes[0] / D;
    const int na  = in_sizes[2] / (D * H);

    if (Brt != NB || na != NA || ws_size < WS_NEEDED) {
        aspect_mlp_fallback<<<Brt, 256, 0, stream>>>(
            X, aspect_ids, W1_embs, b1_embs, W2_embs, b2_embs, out);
        return;
    }

    unsigned short* part = (unsigned short*)d_ws;

    gemm1_kernel<<<NA * HSN * DKN, 256, 0, stream>>>(
        X, aspect_ids, W1_embs, b1_embs, part);
    finish_kernel<<<NB / 8, 256, 0, stream>>>(
        aspect_ids, part, W2_embs, b2_embs, out);
}

// Round 17
// 13.767 us; speedup vs baseline: 3.0398x; 1.0576x over previous
//
#include <hip/hip_runtime.h>

// MFMA aspect-grouped 2-layer MLP, 2 dispatches, in-LDS transpose.
//   gemm1:  flat 640-block grid: hs=bid/80 (0..7, 32-col slice), p=bid%80,
//           aid=p%20, dk=p/20 (0..3, 192-k slice). hs stride 80 = 0 mod 8 ->
//           the 8 hs-blocks sharing one (aid,dk) X-slice sit on one XCD.
//           Wave 0 ballot-scans aspect_ids (int4, deterministic, identical in
//           every block) -> sidx (padded to x64) while waves 1-3 transpose
//           W1 tile [192k][32c] fp32 -> bf16 W1T_lds [32c][192k] via 4k x 4c
//           subtiles (uint2 writes); one barrier. One X stage [64][192] bf16
//           at b128 (8 floats/iter). Wave role: ct=w&1 col-tile, sh=w>>1
//           sample-half: 32 samples x 16 cols x 192k = 12 MFMA (6 B + 12 A
//           ds_read_b128). bf16 part[sample][dk][col] (+b1 at dk==0).
//   finish: 128 blocks; 2 samples/wave (32 lanes x 8 cols), uint4 part reads
//           (4 dk-partials), ReLU, x W2 + b2 -> out.

constexpr int D  = 768;
constexpr int H  = 256;
constexpr int NA = 20;
constexpr int NB = 1024;
constexpr int S  = 64;            // samples per chunk (aspects avg ~51 -> 1 chunk)
constexpr int DKN = 4;            // d-slices
constexpr int KS  = D / DKN;      // 192 k per block
constexpr int HSN = 8;            // 32-col slices
constexpr int RW  = KS + 8;       // 200 shorts/row (400B, 16B-aligned)

constexpr size_t WS_NEEDED = (size_t)NB * DKN * H * 2;   // bf16 part: 2 MB

typedef __attribute__((ext_vector_type(8))) short short8v;  // 8 bf16
typedef __attribute__((ext_vector_type(4))) float f32x4;

__device__ __forceinline__ unsigned f2bf(float x) {   // RTN-even, low 16
    const unsigned u = __float_as_uint(x);
    return (u + 0x7FFFu + ((u >> 16) & 1u)) >> 16;
}
__device__ __forceinline__ float bflo(unsigned u) { return __uint_as_float(u << 16); }
__device__ __forceinline__ float bfhi(unsigned u) { return __uint_as_float(u & 0xFFFF0000u); }

__global__ __launch_bounds__(256, 3) void gemm1_kernel(
    const float* __restrict__ X,
    const int*   __restrict__ aids,
    const float* __restrict__ W1,
    const float* __restrict__ b1,
    unsigned short* __restrict__ part)   // bf16 [NB][DKN][H]
{
    __shared__ __align__(16) short w1t[32 * RW];   // bf16 W1T [32c][192k]
    __shared__ __align__(16) short xl[S * RW];     // bf16 X   [64s][192k]
    __shared__ int sidx[NB + S];
    __shared__ int n_sh;

    const int t = threadIdx.x;
    const int w = t >> 6, l = t & 63;
    const int bid = blockIdx.x;
    const int hs  = bid / 80;          // 0..7, 32-col slice
    const int p   = bid - hs * 80;     // 0..79
    const int aid = p % NA;            // 0..19
    const int dk  = p / NA;            // 0..3, 192-k slice

    if (w == 0) {
        // wave 0: ballot-scan, int4 loads; deterministic interleaved order,
        // identical in every block.
        int run = 0;
        #pragma unroll
        for (int base = 0; base < NB; base += 256) {
            const int4 v = *reinterpret_cast<const int4*>(&aids[base + l * 4]);
            #pragma unroll
            for (int j = 0; j < 4; ++j) {
                const int id = (j == 0) ? v.x : (j == 1) ? v.y : (j == 2) ? v.z : v.w;
                const unsigned long long m = __ballot(id == aid);
                const int pre = run + __popcll(m & ((1ull << l) - 1));
                if (id == aid) sidx[pre] = base + l * 4 + j;
                run += __popcll(m);
            }
        }
        if (run > 0) {
            const int last = sidx[run - 1];          // own-wave write, ordered
            const int npad = ((run + S - 1) / S) * S;
            if (run + l < npad) sidx[run + l] = last;
        }
        if (l == 0) n_sh = run;
    } else {
        // waves 1-3: W1 tile [192k][32c] -> bf16 W1T_lds [32c][192k].
        // i -> (k-quad kq4 0..47, col-quad cq 0..7): 4 f4 loads (rows
        // 4kq4..+3, cols cq*4..+3), pack 4 k per col -> uint2 write.
        const float* W1s = W1 + (size_t)aid * D * H + (size_t)dk * KS * H + hs * 32;
        uint2* w1v = reinterpret_cast<uint2*>(w1t);   // row c at c*(RW/4) uint2
        for (int i = t - 64; i < (KS / 4) * 8; i += 192) {  // 384 iters, 2 each
            const int kq4 = i >> 3, cq = i & 7;
            const int k0 = kq4 * 4;
            const float4 a = *reinterpret_cast<const float4*>(&W1s[(size_t)(k0 + 0) * H + cq * 4]);
            const float4 b = *reinterpret_cast<const float4*>(&W1s[(size_t)(k0 + 1) * H + cq * 4]);
            const float4 c = *reinterpret_cast<const float4*>(&W1s[(size_t)(k0 + 2) * H + cq * 4]);
            const float4 d = *reinterpret_cast<const float4*>(&W1s[(size_t)(k0 + 3) * H + cq * 4]);
            uint2 o;
            o.x = f2bf(a.x) | (f2bf(b.x) << 16);
            o.y = f2bf(c.x) | (f2bf(d.x) << 16);
            w1v[(cq * 4 + 0) * (RW / 4) + kq4] = o;
            o.x = f2bf(a.y) | (f2bf(b.y) << 16);
            o.y = f2bf(c.y) | (f2bf(d.y) << 16);
            w1v[(cq * 4 + 1) * (RW / 4) + kq4] = o;
            o.x = f2bf(a.z) | (f2bf(b.z) << 16);
            o.y = f2bf(c.z) | (f2bf(d.z) << 16);
            w1v[(cq * 4 + 2) * (RW / 4) + kq4] = o;
            o.x = f2bf(a.w) | (f2bf(b.w) << 16);
            o.y = f2bf(c.w) | (f2bf(d.w) << 16);
            w1v[(cq * 4 + 3) * (RW / 4) + kq4] = o;
        }
    }
    __syncthreads();
    const int n = n_sh;
    if (n == 0) return;                 // uniform exit

    const int cg = l & 15, gq = l >> 4;
    const int ct = w & 1;               // col-tile within 32-col slice
    const int sh = w >> 1;              // sample-half (0: s 0..31, 1: s 32..63)
    const short* wa = &w1t[(ct * 16 + cg) * RW + 8 * gq];
    const int gcol = hs * 32 + ct * 16 + cg;
    const float b1v = (dk == 0) ? b1[(size_t)aid * H + gcol] : 0.f;

    for (int ch = 0; ch * S < n; ++ch) {
        // stage X chunk [64][192] as bf16: 8 floats/iter -> b128 LDS write
        for (int i = t; i < S * (KS / 8); i += 256) {       // 1536 iters, 6 each
            const int r = i / (KS / 8), q8 = i - r * (KS / 8);
            const float* xp = &X[(size_t)sidx[ch * S + r] * D + dk * KS + q8 * 8];
            const float4 v0 = *reinterpret_cast<const float4*>(xp);
            const float4 v1 = *reinterpret_cast<const float4*>(xp + 4);
            uint4 o;
            o.x = f2bf(v0.x) | (f2bf(v0.y) << 16);
            o.y = f2bf(v0.z) | (f2bf(v0.w) << 16);
            o.z = f2bf(v1.x) | (f2bf(v1.y) << 16);
            o.w = f2bf(v1.z) | (f2bf(v1.w) << 16);
            *reinterpret_cast<uint4*>(&xl[r * RW + q8 * 8]) = o;
        }
        __syncthreads();

        // 32 samples x 16 cols x 192k per wave: 12 MFMA, 6 B + 12 A ds_reads
        f32x4 acc0 = {0,0,0,0}, acc1 = {0,0,0,0};
        #pragma unroll
        for (int ks = 0; ks < KS / 32; ++ks) {
            const short8v bv = *reinterpret_cast<const short8v*>(wa + ks * 32);
            const int kof = ks * 32 + 8 * gq;
            acc0 = __builtin_amdgcn_mfma_f32_16x16x32_bf16(
                *reinterpret_cast<const short8v*>(&xl[(sh * 32 + cg)      * RW + kof]), bv, acc0, 0, 0, 0);
            acc1 = __builtin_amdgcn_mfma_f32_16x16x32_bf16(
                *reinterpret_cast<const short8v*>(&xl[(sh * 32 + 16 + cg) * RW + kof]), bv, acc1, 0, 0, 0);
        }

        // D[row=4gq+r][col=cg]; write bf16 partials (guarded: cv)
        const int cv = min(S, n - ch * S);
        #pragma unroll
        for (int r = 0; r < 4; ++r) {
            const int s0 = sh * 32 + gq * 4 + r;
            if (s0 < cv)
                part[((size_t)sidx[ch * S + s0] * DKN + dk) * H + gcol] =
                    (unsigned short)f2bf(acc0[r] + b1v);
            const int s1 = sh * 32 + 16 + gq * 4 + r;
            if (s1 < cv)
                part[((size_t)sidx[ch * S + s1] * DKN + dk) * H + gcol] =
                    (unsigned short)f2bf(acc1[r] + b1v);
        }
        if ((ch + 1) * S < n) __syncthreads();   // only when another chunk follows
    }
}

__global__ __launch_bounds__(256) void finish_kernel(
    const int*            __restrict__ aids,
    const unsigned short* __restrict__ part,
    const float*          __restrict__ W2,
    const float*          __restrict__ b2,
    float*                __restrict__ out)
{
    const int w = threadIdx.x >> 6, l = threadIdx.x & 63;
    const int half = l >> 5;                 // 0/1: two samples per wave
    const int m = l & 31;                    // col-octet 0..31
    const int s = blockIdx.x * 8 + w * 2 + half;
    const int aid = aids[s];

    // accumulate 8 cols (m*8 .. m*8+7) over 4 dk-partials, uint4 loads
    const unsigned short* ps = part + (size_t)s * DKN * H + m * 8;
    float v[8] = {0, 0, 0, 0, 0, 0, 0, 0};
    #pragma unroll
    for (int dk = 0; dk < DKN; ++dk) {
        const uint4 r = *reinterpret_cast<const uint4*>(ps + dk * H);
        v[0] += bflo(r.x); v[1] += bfhi(r.x);
        v[2] += bflo(r.y); v[3] += bfhi(r.y);
        v[4] += bflo(r.z); v[5] += bfhi(r.z);
        v[6] += bflo(r.w); v[7] += bfhi(r.w);
    }

    // ReLU + layer-2 dot over these 8 cols
    const float4* W2v = reinterpret_cast<const float4*>(&W2[((size_t)aid * H + m * 8) * 2]);
    float p0 = 0.f, p1 = 0.f;
    #pragma unroll
    for (int c4 = 0; c4 < 4; ++c4) {
        const float4 wv = W2v[c4];           // cols 2c4 (x,y), 2c4+1 (z,w)
        const float o0 = fmaxf(v[c4 * 2 + 0], 0.f);
        const float o1 = fmaxf(v[c4 * 2 + 1], 0.f);
        p0 += o0 * wv.x + o1 * wv.z;
        p1 += o0 * wv.y + o1 * wv.w;
    }

    // reduce across the 32 lanes of this half-wave
    #pragma unroll
    for (int msk = 1; msk < 32; msk <<= 1) {
        p0 += __shfl_xor(p0, msk, 64);
        p1 += __shfl_xor(p1, msk, 64);
    }
    if (m == 0) {
        const float2 b2v = reinterpret_cast<const float2*>(b2)[aid];
        reinterpret_cast<float2*>(out)[s] = make_float2(p0 + b2v.x, p1 + b2v.y);
    }
}

// ---------------- fallback (round-1 monolithic kernel) ----------------
__global__ __launch_bounds__(256, 4) void aspect_mlp_fallback(
    const float* __restrict__ X, const int* __restrict__ aspect_ids,
    const float* __restrict__ W1_embs, const float* __restrict__ b1_embs,
    const float* __restrict__ W2_embs, const float* __restrict__ b2_embs,
    float* __restrict__ out)
{
    __shared__ float xs[D];
    __shared__ float pl[4][H];
    __shared__ float red[4][2];
    const int b = blockIdx.x, t = threadIdx.x, w = t >> 6, l = t & 63;
    const int aid = aspect_ids[b];
    const float4* Xr = reinterpret_cast<const float4*>(X + (size_t)b * D);
    if (t < D / 4) reinterpret_cast<float4*>(xs)[t] = Xr[t];
    __syncthreads();
    const float4* W1v = reinterpret_cast<const float4*>(W1_embs + (size_t)aid * (D * H));
    float4 acc = make_float4(0.f, 0.f, 0.f, 0.f);
    const int d0 = w * (D / 4);
    for (int d = d0; d < d0 + D / 4; ++d) {
        const float xv = xs[d];
        const float4 wv = W1v[d * (H / 4) + l];
        acc.x = fmaf(xv, wv.x, acc.x); acc.y = fmaf(xv, wv.y, acc.y);
        acc.z = fmaf(xv, wv.z, acc.z); acc.w = fmaf(xv, wv.w, acc.w);
    }
    reinterpret_cast<float4*>(pl[w])[l] = acc;
    __syncthreads();
    const float o = fmaxf(pl[0][t] + pl[1][t] + pl[2][t] + pl[3][t] + b1_embs[aid * H + t], 0.f);
    const float2 w2 = reinterpret_cast<const float2*>(W2_embs)[aid * H + t];
    float p0 = o * w2.x, p1 = o * w2.y;
    for (int s = 32; s; s >>= 1) { p0 += __shfl_xor(p0, s, 64); p1 += __shfl_xor(p1, s, 64); }
    if (l == 0) { red[w][0] = p0; red[w][1] = p1; }
    __syncthreads();
    if (t == 0) {
        const float2 bias2 = reinterpret_cast<const float2*>(b2_embs)[aid];
        out[b * 2 + 0] = red[0][0] + red[1][0] + red[2][0] + red[3][0] + bias2.x;
        out[b * 2 + 1] = red[0][1] + red[1][1] + red[2][1] + red[3][1] + bias2.y;
    }
}

extern "C" void kernel_launch(void* const* d_in, const int* in_sizes, int n_in,
                              void* d_out, int out_size, void* d_ws, size_t ws_size,
                              hipStream_t stream) {
    const float* X          = (const float*)d_in[0];
    const int*   aspect_ids = (const int*)d_in[1];
    const float* W1_embs    = (const float*)d_in[2];
    const float* b1_embs    = (const float*)d_in[3];
    const float* W2_embs    = (const float*)d_in[4];
    const float* b2_embs    = (const float*)d_in[5];
    float*       out        = (float*)d_out;

    const int Brt = in_sizes[0] / D;
    const int na  = in_sizes[2] / (D * H);

    if (Brt != NB || na != NA || ws_size < WS_NEEDED) {
        aspect_mlp_fallback<<<Brt, 256, 0, stream>>>(
            X, aspect_ids, W1_embs, b1_embs, W2_embs, b2_embs, out);
        return;
    }

    unsigned short* part = (unsigned short*)d_ws;

    gemm1_kernel<<<NA * HSN * DKN, 256, 0, stream>>>(
        X, aspect_ids, W1_embs, b1_embs, part);
    finish_kernel<<<NB / 8, 256, 0, stream>>>(
        aspect_ids, part, W2_embs, b2_embs, out);
}